// Round 11
// baseline (250.159 us; speedup 1.0000x reference)
//
#include <hip/hip_runtime.h>
#include <hip/hip_bf16.h>

#define S_LEN   1024
#define D_MODEL 768
#define N_HEAD  12
#define D_HEAD  64
#define BATCH   4
#define T_LEN   2047      // 2*S-1
#define INF_VAL 1000000.0f
#define SCALE   0.125f    // 1/sqrt(64)
#define LN_EPSF 1e-9f

typedef __attribute__((ext_vector_type(8))) __bf16 bf8;
typedef __attribute__((ext_vector_type(4))) __bf16 bf4;
typedef __attribute__((ext_vector_type(4))) float  f32x4;

// byte-address XOR swizzle for 128B-stride LDS rows
__device__ __forceinline__ int swz_addr(int row, int byte_in_row) {
    return ((row << 7) + byte_in_row) ^ ((row & 7) << 4);
}

#define GLOAD_LDS(gsrc, ldst) \
    __builtin_amdgcn_global_load_lds( \
        (const __attribute__((address_space(1))) void*)(gsrc), \
        (__attribute__((address_space(3))) void*)(ldst), 16, 0, 0)

// ---------------------------------------------------------------------------
// flag[0]: token_type_mat int32(1)/int8(0).  flag[1]: cls==1 && amask==1.
// ---------------------------------------------------------------------------
__global__ void detect_kernel(const unsigned char* __restrict__ p, int* __restrict__ flag)
{
    int lane = threadIdx.x;          // 64 threads
    int nz = 0;
    int base = lane * 64;
    for (int k = base; k < base + 64; k += 4)
        nz += (p[k+1] != 0) + (p[k+2] != 0) + (p[k+3] != 0);
    unsigned long long m = __ballot(nz != 0);
    if (lane == 0) { flag[0] = (m == 0ull) ? 1 : 0; flag[1] = 1; }
}

// ---------------------------------------------------------------------------
// fp32 -> bf16 bulk convert (query,key,value,r) via blockIdx.z
// ---------------------------------------------------------------------------
__global__ __launch_bounds__(256)
void tobf16_kernel(const float* __restrict__ q, const float* __restrict__ k,
                   const float* __restrict__ v, const float* __restrict__ r,
                   __bf16* __restrict__ qb, __bf16* __restrict__ kb,
                   __bf16* __restrict__ vb, __bf16* __restrict__ rb)
{
    int z = blockIdx.z;
    const float* src; __bf16* dst; size_t n;
    if (z == 0)      { src = q; dst = qb; n = (size_t)4096*768; }
    else if (z == 1) { src = k; dst = kb; n = (size_t)4096*768; }
    else if (z == 2) { src = v; dst = vb; n = (size_t)4096*768; }
    else             { src = r; dst = rb; n = (size_t)T_LEN*768; }
    size_t i = ((size_t)blockIdx.x * 256 + threadIdx.x) * 8;
    if (i + 8 > n) return;
    float4 a = *(const float4*)(src + i);
    float4 b = *(const float4*)(src + i + 4);
    bf8 o;
    o[0]=(__bf16)a.x; o[1]=(__bf16)a.y; o[2]=(__bf16)a.z; o[3]=(__bf16)a.w;
    o[4]=(__bf16)b.x; o[5]=(__bf16)b.y; o[6]=(__bf16)b.z; o[7]=(__bf16)b.w;
    *(bf8*)(dst + i) = o;
}

// ---------------------------------------------------------------------------
// selpack[w] = 64-bit mask; bit k = (token_type_mat[w*64+k] != 0)
// ---------------------------------------------------------------------------
__global__ __launch_bounds__(256)
void prep_sel(const void* __restrict__ ttm, const int* __restrict__ flag,
              unsigned long long* __restrict__ selpack)
{
    size_t widx = (size_t)blockIdx.x * 256 + threadIdx.x;   // 65536 total
    unsigned long long out = 0;
    if (flag[0]) {                       // int32 input
        const int* ip = (const int*)ttm + widx * 64;
        #pragma unroll
        for (int g = 0; g < 16; ++g) {
            int4 a = *(const int4*)(ip + g * 4);
            unsigned long long nib = (a.x ? 1u : 0u) | (a.y ? 2u : 0u)
                                   | (a.z ? 4u : 0u) | (a.w ? 8u : 0u);
            out |= nib << (g * 4);
        }
    } else {                             // int8/bool input
        const unsigned long long* p8 =
            (const unsigned long long*)((const unsigned char*)ttm + widx * 64);
        #pragma unroll
        for (int g = 0; g < 8; ++g) {
            unsigned long long raw = p8[g];
            #pragma unroll
            for (int k = 0; k < 8; ++k)
                if ((raw >> (8*k)) & 0xffull) out |= 1ull << (g*8 + k);
        }
    }
    selpack[widx] = out;
}

// ---------------------------------------------------------------------------
// clsb = bf16(cls); maskadd = -INF*(1-amask); all-ones detection -> flag[1]
// ---------------------------------------------------------------------------
__global__ __launch_bounds__(256)
void clsb_prep(const float* __restrict__ cls, const int* __restrict__ amask,
               __bf16* __restrict__ clsb, float* __restrict__ maskadd,
               int* __restrict__ flag)
{
    size_t idx = ((size_t)blockIdx.x * 256 + threadIdx.x) * 8;
    const float* p = cls + idx;
    float4 a = *(const float4*)p;
    float4 b = *(const float4*)(p + 4);
    bf8 o;
    o[0]=(__bf16)a.x; o[1]=(__bf16)a.y; o[2]=(__bf16)a.z; o[3]=(__bf16)a.w;
    o[4]=(__bf16)b.x; o[5]=(__bf16)b.y; o[6]=(__bf16)b.z; o[7]=(__bf16)b.w;
    *(bf8*)(clsb + idx) = o;
    int ok = (a.x==1.f)&&(a.y==1.f)&&(a.z==1.f)&&(a.w==1.f)
          && (b.x==1.f)&&(b.y==1.f)&&(b.z==1.f)&&(b.w==1.f);
    if (blockIdx.x == 0) {
        for (int j = threadIdx.x; j < BATCH * S_LEN; j += 256) {
            int am = amask[j];
            maskadd[j] = -INF_VAL * (1.f - (float)am);
            ok &= (am == 1);
        }
    }
    ok = __syncthreads_and(ok);
    if (threadIdx.x == 0 && !ok) atomicAnd(flag + 1, 0);
}

// ---------------------------------------------------------------------------
// Wt[n][k] = (bf16) W[k][n]; fused over 5 weight matrices via blockIdx.z
// ---------------------------------------------------------------------------
__global__ __launch_bounds__(256)
void wtrans_kernel(const float* __restrict__ W0, const float* __restrict__ W1,
                   const float* __restrict__ W2, const float* __restrict__ W3,
                   const float* __restrict__ W4,
                   __bf16* __restrict__ T0, __bf16* __restrict__ T1,
                   __bf16* __restrict__ T2, __bf16* __restrict__ T3,
                   __bf16* __restrict__ T4)
{
    const float* W; __bf16* Wt;
    switch (blockIdx.z) {
        case 0: W = W0; Wt = T0; break;
        case 1: W = W1; Wt = T1; break;
        case 2: W = W2; Wt = T2; break;
        case 3: W = W3; Wt = T3; break;
        default: W = W4; Wt = T4; break;
    }
    const int K = 768, N = 768;
    __shared__ float tile[64][65];
    int tid = threadIdx.x;
    int r = tid >> 4, c4 = (tid & 15) * 4;
    int k0 = blockIdx.y * 64, n0 = blockIdx.x * 64;
    #pragma unroll
    for (int rep = 0; rep < 4; ++rep) {
        int row = rep * 16 + r;
        float4 v = *(const float4*)(W + (size_t)(k0 + row) * N + n0 + c4);
        tile[row][c4+0] = v.x; tile[row][c4+1] = v.y;
        tile[row][c4+2] = v.z; tile[row][c4+3] = v.w;
    }
    __syncthreads();
    #pragma unroll
    for (int rep = 0; rep < 4; ++rep) {
        int row = rep * 16 + r;
        bf4 o;
        #pragma unroll
        for (int j = 0; j < 4; ++j) o[j] = (__bf16)tile[c4 + j][row];
        *(bf4*)(Wt + (size_t)(n0 + row) * K + k0 + c4) = o;
    }
}

// ---------------------------------------------------------------------------
// MFMA GEMM tile body (bf16 A), 2-phase register prefetch.
// out_mode: 0 = fp32 row-major, 1 = bf16 row-major,
//           2 = bf16 head-transposed vhT[(b*12+n)*64+d][1024 j]
// ---------------------------------------------------------------------------
__device__ __forceinline__
void gemm_tile_body(const __bf16* __restrict__ A, const __bf16* __restrict__ Bt,
                    const float* __restrict__ bias, void* __restrict__ C,
                    int M, int N, int K, float scale, int has_bias,
                    int out_mode, int m0, int n0, __bf16* As, __bf16* Bs)
{
    int tid = threadIdx.x;
    int lane = tid & 63, w = tid >> 6;
    int grp = lane >> 4, lcol = lane & 15;
    int wm = w >> 1, wn = w & 1;

    auto loadA = [&](int kt, int rep) -> bf8 {
        int id = rep * 256 + tid;
        int row = id >> 3, ch = id & 7;
        int gm = m0 + row; if (gm >= M) gm = M - 1;
        return *(const bf8*)(A + (size_t)gm * K + kt + ch * 8);
    };
    auto loadB = [&](int kt, int rep) -> bf8 {
        int id = rep * 256 + tid;
        int row = id >> 3, ch = id & 7;
        return *(const bf8*)(Bt + (size_t)(n0 + row) * K + kt + ch * 8);
    };

    bf8 aR0 = loadA(0,0), aR1 = loadA(0,1), aR2 = loadA(0,2), aR3 = loadA(0,3);
    bf8 bR0 = loadB(0,0), bR1 = loadB(0,1), bR2 = loadB(0,2), bR3 = loadB(0,3);

    f32x4 acc[4][4] = {};

    for (int kt = 0; kt < K; kt += 64) {
        __syncthreads();
        {   // write phase
            int id0 = tid;
            { int id = 0*256 + id0; int row = id >> 3, ch = id & 7;
              *(bf8*)((char*)As + swz_addr(row, ch*16)) = aR0;
              *(bf8*)((char*)Bs + swz_addr(row, ch*16)) = bR0; }
            { int id = 1*256 + id0; int row = id >> 3, ch = id & 7;
              *(bf8*)((char*)As + swz_addr(row, ch*16)) = aR1;
              *(bf8*)((char*)Bs + swz_addr(row, ch*16)) = bR1; }
            { int id = 2*256 + id0; int row = id >> 3, ch = id & 7;
              *(bf8*)((char*)As + swz_addr(row, ch*16)) = aR2;
              *(bf8*)((char*)Bs + swz_addr(row, ch*16)) = bR2; }
            { int id = 3*256 + id0; int row = id >> 3, ch = id & 7;
              *(bf8*)((char*)As + swz_addr(row, ch*16)) = aR3;
              *(bf8*)((char*)Bs + swz_addr(row, ch*16)) = bR3; }
        }
        __syncthreads();
        if (kt + 64 < K) {
            aR0 = loadA(kt+64,0); aR1 = loadA(kt+64,1); aR2 = loadA(kt+64,2); aR3 = loadA(kt+64,3);
            bR0 = loadB(kt+64,0); bR1 = loadB(kt+64,1); bR2 = loadB(kt+64,2); bR3 = loadB(kt+64,3);
        }
        #pragma unroll
        for (int kk = 0; kk < 2; ++kk) {
            bf8 a[4], bb[4];
            #pragma unroll
            for (int mi = 0; mi < 4; ++mi)
                a[mi] = *(const bf8*)((const char*)As + swz_addr(wm * 64 + mi * 16 + lcol, kk * 64 + grp * 16));
            #pragma unroll
            for (int ni = 0; ni < 4; ++ni)
                bb[ni] = *(const bf8*)((const char*)Bs + swz_addr(wn * 64 + ni * 16 + lcol, kk * 64 + grp * 16));
            #pragma unroll
            for (int mi = 0; mi < 4; ++mi) {
                #pragma unroll
                for (int ni = 0; ni < 4; ++ni)
                    acc[mi][ni] = __builtin_amdgcn_mfma_f32_16x16x32_bf16(a[mi], bb[ni], acc[mi][ni], 0, 0, 0);
            }
        }
    }

    #pragma unroll
    for (int ni = 0; ni < 4; ++ni) {
        int col = n0 + wn * 64 + ni * 16 + lcol;
        float bval = has_bias ? bias[col] : 0.f;
        #pragma unroll
        for (int mi = 0; mi < 4; ++mi) {
            int rbase = m0 + wm * 64 + mi * 16 + grp * 4;
            if (out_mode == 2) {
                int hn = col >> 6, d = col & 63;
                int bb2 = rbase >> 10;
                int j = rbase & 1023;
                bf4 o;
                #pragma unroll
                for (int reg = 0; reg < 4; ++reg)
                    o[reg] = (__bf16)(acc[mi][ni][reg] * scale + bval);
                *(bf4*)((__bf16*)C + ((size_t)(bb2 * N_HEAD + hn) * 64 + d) * 1024 + j) = o;
            } else {
                #pragma unroll
                for (int reg = 0; reg < 4; ++reg) {
                    int row = rbase + reg;
                    if (row < M) {
                        float vv = acc[mi][ni][reg] * scale + bval;
                        if (out_mode == 1) ((__bf16*)C)[(size_t)row * N + col] = (__bf16)vv;
                        else               ((float*)C)[(size_t)row * N + col] = vv;
                    }
                }
            }
        }
    }
}

// ---------------------------------------------------------------------------
// All four projection GEMMs, 1D grid 768, bijective XCD swizzle (768 = 8*96)
// ---------------------------------------------------------------------------
__global__ __launch_bounds__(256, 3)
void proj_gemm(const __bf16* __restrict__ qb, const __bf16* __restrict__ kb,
               const __bf16* __restrict__ vb, const __bf16* __restrict__ rb,
               const __bf16* __restrict__ Wqt, const __bf16* __restrict__ Wkt,
               const __bf16* __restrict__ Wvt, const __bf16* __restrict__ rkt,
               const float* __restrict__ bk, const float* __restrict__ bv,
               __bf16* __restrict__ qh, __bf16* __restrict__ kh,
               __bf16* __restrict__ vhT, __bf16* __restrict__ rhd)
{
    __shared__ __align__(16) __bf16 As[128 * 64];
    __shared__ __align__(16) __bf16 Bs[128 * 64];
    int id = blockIdx.x;
    int wg = (id & 7) * 96 + (id >> 3);    // XCD-contiguous remap
    int z  = wg / 192;
    int rem = wg % 192;
    int by = rem / 6, bx = rem % 6;

    const __bf16* A; const __bf16* Bt; const float* bias; void* C;
    int M; float scale; int has_bias; int omode;
    if (z == 0)      { A = qb; Bt = Wqt; bias = nullptr; C = qh;  M = 4096; scale = SCALE; has_bias = 0; omode = 1; }
    else if (z == 1) { A = kb; Bt = Wkt; bias = bk;      C = kh;  M = 4096; scale = 1.f;   has_bias = 1; omode = 1; }
    else if (z == 2) { A = vb; Bt = Wvt; bias = bv;      C = vhT; M = 4096; scale = 1.f;   has_bias = 1; omode = 2; }
    else             { A = rb; Bt = rkt; bias = nullptr; C = rhd; M = T_LEN; scale = 1.f;  has_bias = 0; omode = 1; }
    int m0 = by * 128, n0 = bx * 128;
    if (m0 >= M) return;
    gemm_tile_body(A, Bt, bias, C, M, 768, 768, scale, has_bias, omode, m0, n0, As, Bs);
}

// ---------------------------------------------------------------------------
// post-projection GEMM, 1D grid 192 (= 8*24), XCD swizzle
// ---------------------------------------------------------------------------
__global__ __launch_bounds__(256, 3)
void post_gemm(const __bf16* __restrict__ av, const __bf16* __restrict__ Wpt,
               const float* __restrict__ bpost, float* __restrict__ ao)
{
    __shared__ __align__(16) __bf16 As[128 * 64];
    __shared__ __align__(16) __bf16 Bs[128 * 64];
    int id = blockIdx.x;
    int wg = (id & 7) * 24 + (id >> 3);
    int by = wg / 6, bx = wg % 6;
    gemm_tile_body(av, Wpt, bpost, ao, 4096, 768, 768, 1.f, 1, 0,
                   by * 128, bx * 128, As, Bs);
}

// ---------------------------------------------------------------------------
// tt[(b*S+i)*NH*2 + n*2 + s2] = sum_h (qh + r_s_bias*scale) * seg_embed
// ---------------------------------------------------------------------------
__global__ __launch_bounds__(256)
void ttbias_kernel(const __bf16* __restrict__ qh, const float* __restrict__ rsb,
                   const float* __restrict__ seg, float* __restrict__ tt)
{
    int idx = blockIdx.x * 256 + threadIdx.x;
    if (idx >= BATCH * S_LEN * N_HEAD * 2) return;
    int s2  = idx & 1;
    int n   = (idx >> 1) % N_HEAD;
    int row = idx / (2 * N_HEAD);
    const __bf16* q  = qh  + (size_t)row * D_MODEL + n * D_HEAD;
    const float* sg = seg + ((size_t)s2 * N_HEAD + n) * D_HEAD;
    const float* rb = rsb + n * D_HEAD;
    float s = 0.f;
    for (int h = 0; h < D_HEAD; ++h) s += ((float)q[h] + rb[h] * SCALE) * sg[h];
    tt[idx] = s;
}

// ---------------------------------------------------------------------------
// MFMA fused attention. grid (16,12,4), 256 thr. R10 structure
// + selpack u64 broadcast token-type masks + R-window register prefetch.
// ---------------------------------------------------------------------------
__global__ __launch_bounds__(256, 3)
void attn_kernel(const __bf16* __restrict__ qh, const __bf16* __restrict__ kh,
                 const __bf16* __restrict__ vhT, const __bf16* __restrict__ rhd,
                 const float* __restrict__ tt, const __bf16* __restrict__ clsb,
                 const unsigned long long* __restrict__ selpack,
                 const float* __restrict__ maskadd,
                 const float* __restrict__ rwb, const float* __restrict__ rrb,
                 const int* __restrict__ flag, __bf16* __restrict__ av)
{
    __shared__ __align__(16) __bf16 Kt[64*64];       // [j][h]
    __shared__ __align__(16) __bf16 Vt[64*64];       // [d][j]  (transposed)
    __shared__ __align__(16) __bf16 Rw[128*64];      // circular window, phys = t & 127
    __shared__ __align__(16) __bf16 Ps[4*16*64];     // per-wave P [il][jl]
    __shared__ __align__(16) __bf16 poss[4*16*84];   // per-wave pos band, stride 84

    int tid = threadIdx.x;
    int i0 = blockIdx.x * 64;
    int n  = blockIdx.y;
    int b  = blockIdx.z;
    int bS = b * S_LEN;
    int n64 = n * D_HEAD;
    int simple = flag[1];

    int lane = tid & 63, w = tid >> 6;
    int grp = lane >> 4, lcol = lane & 15;

    const __bf16* vT = vhT + (size_t)(b * N_HEAD + n) * 64 * 1024;

    // staging coords: thread covers rows srow, srow+32 with 8-elem chunks.
    int srow = tid >> 3;
    int koff = (((tid & 7) * 16) ^ ((srow & 7) << 4)) >> 1;  // pre-swizzled src offset
    int c8s  = (tid & 7) * 8;                                 // plain chunk (R path)

    // ---- Q fragments ----
    bf8 qwA[2], qrA[2];
    {
        size_t qrow = (size_t)(bS + i0 + w*16 + lcol) * D_MODEL + n64;
        #pragma unroll
        for (int kk = 0; kk < 2; ++kk) {
            int kb = kk*32 + grp*8;
            bf8 qv = *(const bf8*)(qh + qrow + kb);
            const float* wbp = rwb + n64 + kb;
            const float* rbp = rrb + n64 + kb;
            #pragma unroll
            for (int q = 0; q < 8; ++q) {
                float f = (float)qv[q];
                qwA[kk][q] = (__bf16)(f + wbp[q] * SCALE);
                qrA[kk][q] = (__bf16)(f + rbp[q] * SCALE);
            }
        }
    }

    // ---- per-row token-type values (j-independent, hoisted) ----
    float t0r[4], t1r[4];
    #pragma unroll
    for (int reg = 0; reg < 4; ++reg) {
        int gi = i0 + w*16 + grp*4 + reg;
        const float* ttrow = tt + (((size_t)(bS + gi)) * N_HEAD + n) * 2;
        t0r[reg] = ttrow[0];
        t1r[reg] = ttrow[1];
    }

    // ---- relative-shift edge fixup value: qr_row1 . r_head[0] ----
    float fixv = 0.f;
    if (i0 == 0) {
        float qv = (float)qh[((size_t)(bS + 1)) * D_MODEL + n64 + lane] + rrb[n64 + lane] * SCALE;
        float rv = (float)rhd[n64 + lane];
        float t = qv * rv;
        #pragma unroll
        for (int m = 32; m; m >>= 1) t += __shfl_xor(t, m, 64);
        fixv = t;
    }
    bool fix = (i0 == 0 && w == 0 && lane == 15);

    float m_run[4] = {-1e30f, -1e30f, -1e30f, -1e30f};
    float l_run[4] = {0.f, 0.f, 0.f, 0.f};
    f32x4 acc[4] = {};
    const f32x4 zero4 = {0.f, 0.f, 0.f, 0.f};

    int w0_0 = -i0 + 961;

    // ---- prologue: load initial 128-row R window into 4 named regs ----
    bf8 rRa, rRb, rRc, rRd;
    {
        int rowl = tid >> 3;       // 0..31
        int t0 = w0_0 + rowl;
        rRa = (t0      >= 0 && t0      < T_LEN) ? *(const bf8*)(rhd + (size_t)(t0     ) * D_MODEL + n64 + c8s) : bf8{};
        rRb = (t0+32   >= 0 && t0+32   < T_LEN) ? *(const bf8*)(rhd + (size_t)(t0+32  ) * D_MODEL + n64 + c8s) : bf8{};
        rRc = (t0+64   >= 0 && t0+64   < T_LEN) ? *(const bf8*)(rhd + (size_t)(t0+64  ) * D_MODEL + n64 + c8s) : bf8{};
        rRd = (t0+96   >= 0 && t0+96   < T_LEN) ? *(const bf8*)(rhd + (size_t)(t0+96  ) * D_MODEL + n64 + c8s) : bf8{};
    }

    for (int jt = 0; jt < 16; ++jt) {
        int j0 = jt * 64;
        int w0 = j0 - i0 + 961;            // window base t
        int rowl = tid >> 3;

        // ---- token-type masks for this jt (broadcast u64, issued early) ----
        unsigned long long selw[4];
        #pragma unroll
        for (int reg = 0; reg < 4; ++reg) {
            int gi = i0 + w*16 + grp*4 + reg;
            selw[reg] = selpack[(size_t)(bS + gi) * 16 + jt];
        }

        __syncthreads();

        // ---- stage K tile (async HBM->LDS, pre-swizzled source) ----
        {
            const __bf16* ks = kh + (size_t)(bS + j0 + srow) * D_MODEL + n64 + koff;
            GLOAD_LDS(ks,                      (char*)Kt + w*1024);
            GLOAD_LDS(ks + (size_t)32*D_MODEL, (char*)Kt + 4096 + w*1024);
        }
        // ---- stage V^T tile (async HBM->LDS) ----
        {
            const __bf16* vs = vT + (size_t)srow * 1024 + j0 + koff;
            GLOAD_LDS(vs,             (char*)Vt + w*1024);
            GLOAD_LDS(vs + 32*1024,   (char*)Vt + 4096 + w*1024);
        }
        // ---- write prefetched R rows to LDS ----
        if (jt == 0) {
            int t0 = w0 + rowl;
            *(bf8*)((char*)Rw + swz_addr( t0       & 127, c8s*2)) = rRa;
            *(bf8*)((char*)Rw + swz_addr((t0 + 32) & 127, c8s*2)) = rRb;
            *(bf8*)((char*)Rw + swz_addr((t0 + 64) & 127, c8s*2)) = rRc;
            *(bf8*)((char*)Rw + swz_addr((t0 + 96) & 127, c8s*2)) = rRd;
        } else {
            int t0 = w0 + 64 + rowl;       // rows prefetched last iteration
            *(bf8*)((char*)Rw + swz_addr( t0       & 127, c8s*2)) = rRa;
            *(bf8*)((char*)Rw + swz_addr((t0 + 32) & 127, c8s*2)) = rRb;
        }
        __syncthreads();

        // ---- prefetch next jt's R rows (latency hides under compute) ----
        if (jt < 15) {
            int tN = w0 + 128 + rowl;      // next iter needs rows w0'+64.. = w0+128..
            rRa = (tN      < T_LEN) ? *(const bf8*)(rhd + (size_t)(tN     ) * D_MODEL + n64 + c8s) : bf8{};
            rRb = (tN + 32 < T_LEN) ? *(const bf8*)(rhd + (size_t)(tN + 32) * D_MODEL + n64 + c8s) : bf8{};
        }

        // ---- content scores ----
        f32x4 sc_[4] = {zero4, zero4, zero4, zero4};
        #pragma unroll
        for (int c = 0; c < 4; ++c) {
            #pragma unroll
            for (int kk = 0; kk < 2; ++kk) {
                bf8 kb2 = *(const bf8*)((const char*)Kt + swz_addr(c*16 + lcol, kk*64 + grp*16));
                sc_[c] = __builtin_amdgcn_mfma_f32_16x16x32_bf16(qwA[kk], kb2, sc_[c], 0, 0, 0);
            }
        }
        // ---- positional: 5 window tiles ----
        int a0 = 3 - w;
        f32x4 pacc[5] = {zero4, zero4, zero4, zero4, zero4};
        #pragma unroll
        for (int pa = 0; pa < 5; ++pa) {
            #pragma unroll
            for (int kk = 0; kk < 2; ++kk) {
                int tr = w0 + (a0 + pa) * 16 + lcol;
                bf8 rb2 = *(const bf8*)((const char*)Rw + swz_addr(tr & 127, kk*64 + grp*16));
                pacc[pa] = __builtin_amdgcn_mfma_f32_16x16x32_bf16(qrA[kk], rb2, pacc[pa], 0, 0, 0);
            }
        }
        __bf16* pw = poss + w * 16 * 84;
        #pragma unroll
        for (int pa = 0; pa < 5; ++pa) {
            #pragma unroll
            for (int reg = 0; reg < 4; ++reg)
                pw[(grp*4 + reg) * 84 + pa*16 + lcol] = (__bf16)pacc[pa][reg];
        }
        asm volatile("s_waitcnt lgkmcnt(0)" ::: "memory");
        __builtin_amdgcn_sched_barrier(0);

        // ---- assemble scores ----
        float sv[4][4];
        if (simple) {
            #pragma unroll
            for (int c = 0; c < 4; ++c) {
                int jl = c*16 + lcol;
                #pragma unroll
                for (int reg = 0; reg < 4; ++reg) {
                    int il = grp*4 + reg;
                    int rr = jl - il + 15;
                    float pv = (float)pw[il * 84 + rr];
                    if (fix && jt == 15 && c == 3 && reg == 0) pv = fixv;
                    float ttv = ((selw[reg] >> jl) & 1ull) ? t1r[reg] : t0r[reg];
                    sv[c][reg] = sc_[c][reg] + pv + ttv;
                }
            }
        } else {
            #pragma unroll
            for (int c = 0; c < 4; ++c) {
                int jl = c*16 + lcol;
                int gj = j0 + jl;
                float ma = maskadd[b * S_LEN + gj];
                #pragma unroll
                for (int reg = 0; reg < 4; ++reg) {
                    int il = grp*4 + reg;
                    int gi = i0 + w*16 + il;
                    int rr = jl - il + 15;
                    float pv = (float)pw[il * 84 + rr];
                    if (fix && jt == 15 && c == 3 && reg == 0) pv = fixv;
                    float clv = (float)clsb[(size_t)gi * S_LEN + gj];
                    float ttv = ((selw[reg] >> jl) & 1ull) ? t1r[reg] : t0r[reg];
                    sv[c][reg] = sc_[c][reg] + clv * (pv + ttv) + ma;
                }
            }
        }

        // ---- online softmax ----
        float mx[4], alpha[4], rs[4];
        #pragma unroll
        for (int reg = 0; reg < 4; ++reg)
            mx[reg] = fmaxf(fmaxf(sv[0][reg], sv[1][reg]), fmaxf(sv[2][reg], sv[3][reg]));
        #pragma unroll
        for (int msk = 1; msk < 16; msk <<= 1) {
            #pragma unroll
            for (int reg = 0; reg < 4; ++reg)
                mx[reg] = fmaxf(mx[reg], __shfl_xor(mx[reg], msk, 64));
        }
        #pragma unroll
        for (int reg = 0; reg < 4; ++reg) {
            float mn = fmaxf(m_run[reg], mx[reg]);
            alpha[reg] = __expf(m_run[reg] - mn);
            m_run[reg] = mn;
            rs[reg] = 0.f;
        }
        __bf16* psw = Ps;
        #pragma unroll
        for (int c = 0; c < 4; ++c) {
            int jl = c*16 + lcol;
            #pragma unroll
            for (int reg = 0; reg < 4; ++reg) {
                int il = grp*4 + reg;
                float p = __expf(sv[c][reg] - m_run[reg]);
                rs[reg] += p;
                *((__bf16*)((char*)psw + w*2048 + swz_addr(il, jl*2))) = (__bf16)p;
            }
        }
        #pragma unroll
        for (int msk = 1; msk < 16; msk <<= 1) {
            #pragma unroll
            for (int reg = 0; reg < 4; ++reg)
                rs[reg] += __shfl_xor(rs[reg], msk, 64);
        }
        #pragma unroll
        for (int reg = 0; reg < 4; ++reg)
            l_run[reg] = l_run[reg] * alpha[reg] + rs[reg];
        #pragma unroll
        for (int c = 0; c < 4; ++c) {
            #pragma unroll
            for (int reg = 0; reg < 4; ++reg) acc[c][reg] *= alpha[reg];
        }
        asm volatile("s_waitcnt lgkmcnt(0)" ::: "memory");
        __builtin_amdgcn_sched_barrier(0);

        // ---- PV ----
        bf8 pA[2];
        #pragma unroll
        for (int kk = 0; kk < 2; ++kk)
            pA[kk] = *(const bf8*)((const char*)psw + w*2048 + swz_addr(lcol, kk*64 + grp*16));
        #pragma unroll
        for (int c = 0; c < 4; ++c) {
            #pragma unroll
            for (int kk = 0; kk < 2; ++kk) {
                bf8 vb2 = *(const bf8*)((const char*)Vt + swz_addr(c*16 + lcol, kk*64 + grp*16));
                acc[c] = __builtin_amdgcn_mfma_f32_16x16x32_bf16(pA[kk], vb2, acc[c], 0, 0, 0);
            }
        }
    }

    // ---- epilogue (bf16 out) ----
    float inv[4];
    #pragma unroll
    for (int reg = 0; reg < 4; ++reg) inv[reg] = 1.f / l_run[reg];
    #pragma unroll
    for (int c = 0; c < 4; ++c) {
        #pragma unroll
        for (int reg = 0; reg < 4; ++reg) {
            size_t o = ((size_t)(bS + i0 + w*16 + grp*4 + reg)) * D_MODEL + n64 + c*16 + lcol;
            av[o] = (__bf16)(acc[c][reg] * inv[reg]);
        }
    }
}

// ---------------------------------------------------------------------------
// LayerNorm(query + attn_out) * g + b
// ---------------------------------------------------------------------------
__global__ __launch_bounds__(256)
void ln_kernel(const float* __restrict__ query, const float* __restrict__ ao,
               const float* __restrict__ gam, const float* __restrict__ bet,
               float* __restrict__ out)
{
    int row = blockIdx.x;
    int tid = threadIdx.x;
    size_t base = (size_t)row * D_MODEL;
    float xv[3];
    float s = 0.f, sq = 0.f;
    #pragma unroll
    for (int k = 0; k < 3; ++k) {
        int c = tid + k * 256;
        float v = query[base + c] + ao[base + c];
        xv[k] = v; s += v; sq += v * v;
    }
    for (int off = 32; off > 0; off >>= 1) {
        s  += __shfl_down(s, off);
        sq += __shfl_down(sq, off);
    }
    __shared__ float rs[4], rq[4];
    __shared__ float mean_s, inv_s;
    int wid = tid >> 6, lane = tid & 63;
    if (lane == 0) { rs[wid] = s; rq[wid] = sq; }
    __syncthreads();
    if (tid == 0) {
        float S0 = rs[0] + rs[1] + rs[2] + rs[3];
        float Q0 = rq[0] + rq[1] + rq[2] + rq[3];
        float mean = S0 / (float)D_MODEL;
        float var  = Q0 / (float)D_MODEL - mean * mean;
        mean_s = mean;
        inv_s  = rsqrtf(var + LN_EPSF);
    }
    __syncthreads();
    float mean = mean_s, inv = inv_s;
    #pragma unroll
    for (int k = 0; k < 3; ++k) {
        int c = tid + k * 256;
        out[base + c] = (xv[k] - mean) * inv * gam[c] + bet[c];
    }
}

// ---------------------------------------------------------------------------
extern "C" void kernel_launch(void* const* d_in, const int* in_sizes, int n_in,
                              void* d_out, int out_size, void* d_ws, size_t ws_size,
                              hipStream_t stream)
{
    const float* query = (const float*)d_in[0];
    const float* key   = (const float*)d_in[1];
    const float* value = (const float*)d_in[2];
    const float* r     = (const float*)d_in[3];
    const void*  ttm   = d_in[4];
    const int*   amask = (const int*)d_in[5];
    const float* cls   = (const float*)d_in[6];
    const float* Wq    = (const float*)d_in[7];
    const float* Wk    = (const float*)d_in[8];
    const float* bk    = (const float*)d_in[9];
    const float* Wv    = (const float*)d_in[10];
    const float* bv    = (const float*)d_in[11];
    const float* Wpost = (const float*)d_in[12];
    const float* bpost = (const float*)d_in[13];
    const float* ln_g  = (const float*)d_in[14];
    const float* ln_b  = (const float*)d_in[15];
    const float* rwb   = (const float*)d_in[16];
    const float* rrb   = (const float*)d_in[17];
    const float* rker  = (const float*)d_in[18];
    const float* rsb   = (const float*)d_in[19];
    const float* seg   = (const float*)d_in[20];

    char* wsb = (char*)d_ws;
    __bf16* qh  = (__bf16*)(wsb);                    //  6,291,456
    __bf16* kh  = (__bf16*)(wsb + 6291456);
    __bf16* vhT = (__bf16*)(wsb + 12582912);         //  6,291,456  [b][n][64 d][1024 j]
    __bf16* rhd = (__bf16*)(wsb + 18874368);         //  3,145,728
    float*  tt  = (float*) (wsb + 22020096);         //    393,216
    __bf16* av  = (__bf16*)(wsb + 22413312);         //  6,291,456 (qin_b before attn)
    float*  ao  = (float*) (wsb + 28704768);         // 12,582,912 (kin_b before post)
    __bf16* Wqt = (__bf16*)(wsb + 41287680);         //  1,179,648 each
    __bf16* Wkt = (__bf16*)(wsb + 42467328);
    __bf16* Wvt = (__bf16*)(wsb + 43646976);
    __bf16* Wpt = (__bf16*)(wsb + 44826624);
    __bf16* rkt = (__bf16*)(wsb + 46006272);
    int*    flag = (int*)  (wsb + 47185920);         //        256
    unsigned long long* selpack = (unsigned long long*)(wsb + 47186176); // 524,288
    __bf16* clsb    = (__bf16*)(wsb + 51380480);                // 2,097,152
    float*  maskadd = (float*) (wsb + 53477632);                //    16,384
    __bf16* rin_b   = (__bf16*)(wsb + 53494016);                // 3,145,728

    // input bf16 copies overlapping later-written buffers (lifetimes disjoint)
    __bf16* qin_b = av;                 // av written by attn (after proj)
    __bf16* kin_b = (__bf16*)ao;        // ao written by post_gemm (after attn)
    __bf16* vin_b = (__bf16*)(wsb + 34996224);

    detect_kernel<<<1, 64, 0, stream>>>((const unsigned char*)ttm, flag);
    tobf16_kernel<<<dim3(1536, 1, 4), 256, 0, stream>>>(query, key, value, r,
                                                        qin_b, kin_b, vin_b, rin_b);
    prep_sel<<<256, 256, 0, stream>>>(ttm, flag, selpack);
    clsb_prep<<<512, 256, 0, stream>>>(cls, amask, clsb, maskadd, flag);

    dim3 gtr(12, 12, 5);
    wtrans_kernel<<<gtr, 256, 0, stream>>>(Wq, Wk, Wv, Wpost, rker,
                                           Wqt, Wkt, Wvt, Wpt, rkt);

    proj_gemm<<<768, 256, 0, stream>>>(qin_b, kin_b, vin_b, rin_b,
                                       Wqt, Wkt, Wvt, rkt, bk, bv,
                                       qh, kh, vhT, rhd);

    ttbias_kernel<<<384, 256, 0, stream>>>(qh, rsb, seg, tt);

    dim3 gattn(16, 12, 4);
    attn_kernel<<<gattn, 256, 0, stream>>>(qh, kh, vhT, rhd, tt, clsb, selpack,
                                           maskadd, rwb, rrb, flag, av);

    post_gemm<<<192, 256, 0, stream>>>(av, Wpt, bpost, ao);

    ln_kernel<<<4096, 256, 0, stream>>>(query, ao, ln_g, ln_b, (float*)d_out);
}

// Round 12
// 191.589 us; speedup vs baseline: 1.3057x; 1.3057x over previous
//
#include <hip/hip_runtime.h>
#include <hip/hip_bf16.h>

#define S_LEN   1024
#define D_MODEL 768
#define N_HEAD  12
#define D_HEAD  64
#define BATCH   4
#define T_LEN   2047      // 2*S-1
#define INF_VAL 1000000.0f
#define SCALE   0.125f    // 1/sqrt(64)
#define LN_EPSF 1e-9f

typedef __attribute__((ext_vector_type(8))) __bf16 bf8;
typedef __attribute__((ext_vector_type(4))) __bf16 bf4;
typedef __attribute__((ext_vector_type(4))) float  f32x4;

// byte-address XOR swizzle for 128B-stride LDS rows
__device__ __forceinline__ int swz_addr(int row, int byte_in_row) {
    return ((row << 7) + byte_in_row) ^ ((row & 7) << 4);
}

#define GLOAD_LDS(gsrc, ldst) \
    __builtin_amdgcn_global_load_lds( \
        (const __attribute__((address_space(1))) void*)(gsrc), \
        (__attribute__((address_space(3))) void*)(ldst), 16, 0, 0)

// ---------------------------------------------------------------------------
// flag[0]: token_type_mat int32(1)/int8(0).  flag[1]: cls==1 && amask==1.
// ---------------------------------------------------------------------------
__global__ void detect_kernel(const unsigned char* __restrict__ p, int* __restrict__ flag)
{
    int lane = threadIdx.x;          // 64 threads
    int nz = 0;
    int base = lane * 64;
    for (int k = base; k < base + 64; k += 4)
        nz += (p[k+1] != 0) + (p[k+2] != 0) + (p[k+3] != 0);
    unsigned long long m = __ballot(nz != 0);
    if (lane == 0) { flag[0] = (m == 0ull) ? 1 : 0; flag[1] = 1; }
}

// ---------------------------------------------------------------------------
// fp32 -> bf16 bulk convert (query,key,value,r) via blockIdx.z
// ---------------------------------------------------------------------------
__global__ __launch_bounds__(256)
void tobf16_kernel(const float* __restrict__ q, const float* __restrict__ k,
                   const float* __restrict__ v, const float* __restrict__ r,
                   __bf16* __restrict__ qb, __bf16* __restrict__ kb,
                   __bf16* __restrict__ vb, __bf16* __restrict__ rb)
{
    int z = blockIdx.z;
    const float* src; __bf16* dst; size_t n;
    if (z == 0)      { src = q; dst = qb; n = (size_t)4096*768; }
    else if (z == 1) { src = k; dst = kb; n = (size_t)4096*768; }
    else if (z == 2) { src = v; dst = vb; n = (size_t)4096*768; }
    else             { src = r; dst = rb; n = (size_t)T_LEN*768; }
    size_t i = ((size_t)blockIdx.x * 256 + threadIdx.x) * 8;
    if (i + 8 > n) return;
    float4 a = *(const float4*)(src + i);
    float4 b = *(const float4*)(src + i + 4);
    bf8 o;
    o[0]=(__bf16)a.x; o[1]=(__bf16)a.y; o[2]=(__bf16)a.z; o[3]=(__bf16)a.w;
    o[4]=(__bf16)b.x; o[5]=(__bf16)b.y; o[6]=(__bf16)b.z; o[7]=(__bf16)b.w;
    *(bf8*)(dst + i) = o;
}

// ---------------------------------------------------------------------------
// selpack[w] = 64-bit mask; bit k = (token_type_mat[w*64+k] != 0)
// ---------------------------------------------------------------------------
__global__ __launch_bounds__(256)
void prep_sel(const void* __restrict__ ttm, const int* __restrict__ flag,
              unsigned long long* __restrict__ selpack)
{
    size_t widx = (size_t)blockIdx.x * 256 + threadIdx.x;   // 65536 total
    unsigned long long out = 0;
    if (flag[0]) {                       // int32 input
        const int* ip = (const int*)ttm + widx * 64;
        #pragma unroll
        for (int g = 0; g < 16; ++g) {
            int4 a = *(const int4*)(ip + g * 4);
            unsigned long long nib = (a.x ? 1u : 0u) | (a.y ? 2u : 0u)
                                   | (a.z ? 4u : 0u) | (a.w ? 8u : 0u);
            out |= nib << (g * 4);
        }
    } else {                             // int8/bool input
        const unsigned long long* p8 =
            (const unsigned long long*)((const unsigned char*)ttm + widx * 64);
        #pragma unroll
        for (int g = 0; g < 8; ++g) {
            unsigned long long raw = p8[g];
            #pragma unroll
            for (int k = 0; k < 8; ++k)
                if ((raw >> (8*k)) & 0xffull) out |= 1ull << (g*8 + k);
        }
    }
    selpack[widx] = out;
}

// ---------------------------------------------------------------------------
// clsb = bf16(cls); maskadd = -INF*(1-amask); all-ones detection -> flag[1]
// ---------------------------------------------------------------------------
__global__ __launch_bounds__(256)
void clsb_prep(const float* __restrict__ cls, const int* __restrict__ amask,
               __bf16* __restrict__ clsb, float* __restrict__ maskadd,
               int* __restrict__ flag)
{
    size_t idx = ((size_t)blockIdx.x * 256 + threadIdx.x) * 8;
    const float* p = cls + idx;
    float4 a = *(const float4*)p;
    float4 b = *(const float4*)(p + 4);
    bf8 o;
    o[0]=(__bf16)a.x; o[1]=(__bf16)a.y; o[2]=(__bf16)a.z; o[3]=(__bf16)a.w;
    o[4]=(__bf16)b.x; o[5]=(__bf16)b.y; o[6]=(__bf16)b.z; o[7]=(__bf16)b.w;
    *(bf8*)(clsb + idx) = o;
    int ok = (a.x==1.f)&&(a.y==1.f)&&(a.z==1.f)&&(a.w==1.f)
          && (b.x==1.f)&&(b.y==1.f)&&(b.z==1.f)&&(b.w==1.f);
    if (blockIdx.x == 0) {
        for (int j = threadIdx.x; j < BATCH * S_LEN; j += 256) {
            int am = amask[j];
            maskadd[j] = -INF_VAL * (1.f - (float)am);
            ok &= (am == 1);
        }
    }
    ok = __syncthreads_and(ok);
    if (threadIdx.x == 0 && !ok) atomicAnd(flag + 1, 0);
}

// ---------------------------------------------------------------------------
// Wt[n][k] = (bf16) W[k][n]; fused over 5 weight matrices via blockIdx.z
// ---------------------------------------------------------------------------
__global__ __launch_bounds__(256)
void wtrans_kernel(const float* __restrict__ W0, const float* __restrict__ W1,
                   const float* __restrict__ W2, const float* __restrict__ W3,
                   const float* __restrict__ W4,
                   __bf16* __restrict__ T0, __bf16* __restrict__ T1,
                   __bf16* __restrict__ T2, __bf16* __restrict__ T3,
                   __bf16* __restrict__ T4)
{
    const float* W; __bf16* Wt;
    switch (blockIdx.z) {
        case 0: W = W0; Wt = T0; break;
        case 1: W = W1; Wt = T1; break;
        case 2: W = W2; Wt = T2; break;
        case 3: W = W3; Wt = T3; break;
        default: W = W4; Wt = T4; break;
    }
    const int K = 768, N = 768;
    __shared__ float tile[64][65];
    int tid = threadIdx.x;
    int r = tid >> 4, c4 = (tid & 15) * 4;
    int k0 = blockIdx.y * 64, n0 = blockIdx.x * 64;
    #pragma unroll
    for (int rep = 0; rep < 4; ++rep) {
        int row = rep * 16 + r;
        float4 v = *(const float4*)(W + (size_t)(k0 + row) * N + n0 + c4);
        tile[row][c4+0] = v.x; tile[row][c4+1] = v.y;
        tile[row][c4+2] = v.z; tile[row][c4+3] = v.w;
    }
    __syncthreads();
    #pragma unroll
    for (int rep = 0; rep < 4; ++rep) {
        int row = rep * 16 + r;
        bf4 o;
        #pragma unroll
        for (int j = 0; j < 4; ++j) o[j] = (__bf16)tile[c4 + j][row];
        *(bf4*)(Wt + (size_t)(n0 + row) * K + k0 + c4) = o;
    }
}

// ---------------------------------------------------------------------------
// MFMA GEMM tile body (bf16 A), 2-phase register prefetch.
// out_mode: 0 = fp32 row-major, 1 = bf16 row-major,
//           2 = bf16 head-transposed vhT[(b*12+n)*64+d][1024 j]
// ---------------------------------------------------------------------------
__device__ __forceinline__
void gemm_tile_body(const __bf16* __restrict__ A, const __bf16* __restrict__ Bt,
                    const float* __restrict__ bias, void* __restrict__ C,
                    int M, int N, int K, float scale, int has_bias,
                    int out_mode, int m0, int n0, __bf16* As, __bf16* Bs)
{
    int tid = threadIdx.x;
    int lane = tid & 63, w = tid >> 6;
    int grp = lane >> 4, lcol = lane & 15;
    int wm = w >> 1, wn = w & 1;

    auto loadA = [&](int kt, int rep) -> bf8 {
        int id = rep * 256 + tid;
        int row = id >> 3, ch = id & 7;
        int gm = m0 + row; if (gm >= M) gm = M - 1;
        return *(const bf8*)(A + (size_t)gm * K + kt + ch * 8);
    };
    auto loadB = [&](int kt, int rep) -> bf8 {
        int id = rep * 256 + tid;
        int row = id >> 3, ch = id & 7;
        return *(const bf8*)(Bt + (size_t)(n0 + row) * K + kt + ch * 8);
    };

    bf8 aR0 = loadA(0,0), aR1 = loadA(0,1), aR2 = loadA(0,2), aR3 = loadA(0,3);
    bf8 bR0 = loadB(0,0), bR1 = loadB(0,1), bR2 = loadB(0,2), bR3 = loadB(0,3);

    f32x4 acc[4][4] = {};

    for (int kt = 0; kt < K; kt += 64) {
        __syncthreads();
        {   // write phase
            int id0 = tid;
            { int id = 0*256 + id0; int row = id >> 3, ch = id & 7;
              *(bf8*)((char*)As + swz_addr(row, ch*16)) = aR0;
              *(bf8*)((char*)Bs + swz_addr(row, ch*16)) = bR0; }
            { int id = 1*256 + id0; int row = id >> 3, ch = id & 7;
              *(bf8*)((char*)As + swz_addr(row, ch*16)) = aR1;
              *(bf8*)((char*)Bs + swz_addr(row, ch*16)) = bR1; }
            { int id = 2*256 + id0; int row = id >> 3, ch = id & 7;
              *(bf8*)((char*)As + swz_addr(row, ch*16)) = aR2;
              *(bf8*)((char*)Bs + swz_addr(row, ch*16)) = bR2; }
            { int id = 3*256 + id0; int row = id >> 3, ch = id & 7;
              *(bf8*)((char*)As + swz_addr(row, ch*16)) = aR3;
              *(bf8*)((char*)Bs + swz_addr(row, ch*16)) = bR3; }
        }
        __syncthreads();
        if (kt + 64 < K) {
            aR0 = loadA(kt+64,0); aR1 = loadA(kt+64,1); aR2 = loadA(kt+64,2); aR3 = loadA(kt+64,3);
            bR0 = loadB(kt+64,0); bR1 = loadB(kt+64,1); bR2 = loadB(kt+64,2); bR3 = loadB(kt+64,3);
        }
        #pragma unroll
        for (int kk = 0; kk < 2; ++kk) {
            bf8 a[4], bb[4];
            #pragma unroll
            for (int mi = 0; mi < 4; ++mi)
                a[mi] = *(const bf8*)((const char*)As + swz_addr(wm * 64 + mi * 16 + lcol, kk * 64 + grp * 16));
            #pragma unroll
            for (int ni = 0; ni < 4; ++ni)
                bb[ni] = *(const bf8*)((const char*)Bs + swz_addr(wn * 64 + ni * 16 + lcol, kk * 64 + grp * 16));
            #pragma unroll
            for (int mi = 0; mi < 4; ++mi) {
                #pragma unroll
                for (int ni = 0; ni < 4; ++ni)
                    acc[mi][ni] = __builtin_amdgcn_mfma_f32_16x16x32_bf16(a[mi], bb[ni], acc[mi][ni], 0, 0, 0);
            }
        }
    }

    #pragma unroll
    for (int ni = 0; ni < 4; ++ni) {
        int col = n0 + wn * 64 + ni * 16 + lcol;
        float bval = has_bias ? bias[col] : 0.f;
        #pragma unroll
        for (int mi = 0; mi < 4; ++mi) {
            int rbase = m0 + wm * 64 + mi * 16 + grp * 4;
            if (out_mode == 2) {
                int hn = col >> 6, d = col & 63;
                int bb2 = rbase >> 10;
                int j = rbase & 1023;
                bf4 o;
                #pragma unroll
                for (int reg = 0; reg < 4; ++reg)
                    o[reg] = (__bf16)(acc[mi][ni][reg] * scale + bval);
                *(bf4*)((__bf16*)C + ((size_t)(bb2 * N_HEAD + hn) * 64 + d) * 1024 + j) = o;
            } else {
                #pragma unroll
                for (int reg = 0; reg < 4; ++reg) {
                    int row = rbase + reg;
                    if (row < M) {
                        float vv = acc[mi][ni][reg] * scale + bval;
                        if (out_mode == 1) ((__bf16*)C)[(size_t)row * N + col] = (__bf16)vv;
                        else               ((float*)C)[(size_t)row * N + col] = vv;
                    }
                }
            }
        }
    }
}

// ---------------------------------------------------------------------------
// All four projection GEMMs, 1D grid 768, bijective XCD swizzle (768 = 8*96)
// ---------------------------------------------------------------------------
__global__ __launch_bounds__(256, 3)
void proj_gemm(const __bf16* __restrict__ qb, const __bf16* __restrict__ kb,
               const __bf16* __restrict__ vb, const __bf16* __restrict__ rb,
               const __bf16* __restrict__ Wqt, const __bf16* __restrict__ Wkt,
               const __bf16* __restrict__ Wvt, const __bf16* __restrict__ rkt,
               const float* __restrict__ bk, const float* __restrict__ bv,
               __bf16* __restrict__ qh, __bf16* __restrict__ kh,
               __bf16* __restrict__ vhT, __bf16* __restrict__ rhd)
{
    __shared__ __align__(16) __bf16 As[128 * 64];
    __shared__ __align__(16) __bf16 Bs[128 * 64];
    int id = blockIdx.x;
    int wg = (id & 7) * 96 + (id >> 3);    // XCD-contiguous remap
    int z  = wg / 192;
    int rem = wg % 192;
    int by = rem / 6, bx = rem % 6;

    const __bf16* A; const __bf16* Bt; const float* bias; void* C;
    int M; float scale; int has_bias; int omode;
    if (z == 0)      { A = qb; Bt = Wqt; bias = nullptr; C = qh;  M = 4096; scale = SCALE; has_bias = 0; omode = 1; }
    else if (z == 1) { A = kb; Bt = Wkt; bias = bk;      C = kh;  M = 4096; scale = 1.f;   has_bias = 1; omode = 1; }
    else if (z == 2) { A = vb; Bt = Wvt; bias = bv;      C = vhT; M = 4096; scale = 1.f;   has_bias = 1; omode = 2; }
    else             { A = rb; Bt = rkt; bias = nullptr; C = rhd; M = T_LEN; scale = 1.f;  has_bias = 0; omode = 1; }
    int m0 = by * 128, n0 = bx * 128;
    if (m0 >= M) return;
    gemm_tile_body(A, Bt, bias, C, M, 768, 768, scale, has_bias, omode, m0, n0, As, Bs);
}

// ---------------------------------------------------------------------------
// post-projection GEMM, 1D grid 192 (= 8*24), XCD swizzle
// ---------------------------------------------------------------------------
__global__ __launch_bounds__(256, 3)
void post_gemm(const __bf16* __restrict__ av, const __bf16* __restrict__ Wpt,
               const float* __restrict__ bpost, float* __restrict__ ao)
{
    __shared__ __align__(16) __bf16 As[128 * 64];
    __shared__ __align__(16) __bf16 Bs[128 * 64];
    int id = blockIdx.x;
    int wg = (id & 7) * 24 + (id >> 3);
    int by = wg / 6, bx = wg % 6;
    gemm_tile_body(av, Wpt, bpost, ao, 4096, 768, 768, 1.f, 1, 0,
                   by * 128, bx * 128, As, Bs);
}

// ---------------------------------------------------------------------------
// tt[(b*S+i)*NH*2 + n*2 + s2] = sum_h (qh + r_s_bias*scale) * seg_embed
// ---------------------------------------------------------------------------
__global__ __launch_bounds__(256)
void ttbias_kernel(const __bf16* __restrict__ qh, const float* __restrict__ rsb,
                   const float* __restrict__ seg, float* __restrict__ tt)
{
    int idx = blockIdx.x * 256 + threadIdx.x;
    if (idx >= BATCH * S_LEN * N_HEAD * 2) return;
    int s2  = idx & 1;
    int n   = (idx >> 1) % N_HEAD;
    int row = idx / (2 * N_HEAD);
    const __bf16* q  = qh  + (size_t)row * D_MODEL + n * D_HEAD;
    const float* sg = seg + ((size_t)s2 * N_HEAD + n) * D_HEAD;
    const float* rb = rsb + n * D_HEAD;
    float s = 0.f;
    for (int h = 0; h < D_HEAD; ++h) s += ((float)q[h] + rb[h] * SCALE) * sg[h];
    tt[idx] = s;
}

// ---------------------------------------------------------------------------
// MFMA fused attention. grid (16,12,4), 256 thr. R10 structure (proven 90us)
// + selpack u64 masks loaded AT POINT OF USE in assemble (short lifetime).
// ---------------------------------------------------------------------------
__global__ __launch_bounds__(256, 3)
void attn_kernel(const __bf16* __restrict__ qh, const __bf16* __restrict__ kh,
                 const __bf16* __restrict__ vhT, const __bf16* __restrict__ rhd,
                 const float* __restrict__ tt, const __bf16* __restrict__ clsb,
                 const unsigned long long* __restrict__ selpack,
                 const float* __restrict__ maskadd,
                 const float* __restrict__ rwb, const float* __restrict__ rrb,
                 const int* __restrict__ flag, __bf16* __restrict__ av)
{
    __shared__ __align__(16) __bf16 Kt[64*64];       // [j][h]
    __shared__ __align__(16) __bf16 Vt[64*64];       // [d][j]  (transposed)
    __shared__ __align__(16) __bf16 Rw[128*64];      // circular window, phys = t & 127
    __shared__ __align__(16) __bf16 Ps[4*16*64];     // per-wave P [il][jl]
    __shared__ __align__(16) __bf16 poss[4*16*84];   // per-wave pos band, stride 84

    int tid = threadIdx.x;
    int i0 = blockIdx.x * 64;
    int n  = blockIdx.y;
    int b  = blockIdx.z;
    int bS = b * S_LEN;
    int n64 = n * D_HEAD;
    int simple = flag[1];

    int lane = tid & 63, w = tid >> 6;
    int grp = lane >> 4, lcol = lane & 15;

    const __bf16* vT = vhT + (size_t)(b * N_HEAD + n) * 64 * 1024;

    // staging coords: thread covers rows srow, srow+32 with 8-elem chunks.
    // pre-swizzled source offset (elements); (srow+32)&7 == srow&7.
    int srow = tid >> 3;
    int koff = (((tid & 7) * 16) ^ ((srow & 7) << 4)) >> 1;

    // ---- Q fragments ----
    bf8 qwA[2], qrA[2];
    {
        size_t qrow = (size_t)(bS + i0 + w*16 + lcol) * D_MODEL + n64;
        #pragma unroll
        for (int kk = 0; kk < 2; ++kk) {
            int kb = kk*32 + grp*8;
            bf8 qv = *(const bf8*)(qh + qrow + kb);
            const float* wbp = rwb + n64 + kb;
            const float* rbp = rrb + n64 + kb;
            #pragma unroll
            for (int q = 0; q < 8; ++q) {
                float f = (float)qv[q];
                qwA[kk][q] = (__bf16)(f + wbp[q] * SCALE);
                qrA[kk][q] = (__bf16)(f + rbp[q] * SCALE);
            }
        }
    }

    // ---- per-row token-type values (j-independent, hoisted) ----
    float t0r[4], t1r[4];
    #pragma unroll
    for (int reg = 0; reg < 4; ++reg) {
        int gi = i0 + w*16 + grp*4 + reg;
        const float* ttrow = tt + (((size_t)(bS + gi)) * N_HEAD + n) * 2;
        t0r[reg] = ttrow[0];
        t1r[reg] = ttrow[1];
    }

    // ---- relative-shift edge fixup value: qr_row1 . r_head[0] ----
    float fixv = 0.f;
    if (i0 == 0) {
        float qv = (float)qh[((size_t)(bS + 1)) * D_MODEL + n64 + lane] + rrb[n64 + lane] * SCALE;
        float rv = (float)rhd[n64 + lane];
        float t = qv * rv;
        #pragma unroll
        for (int m = 32; m; m >>= 1) t += __shfl_xor(t, m, 64);
        fixv = t;
    }
    bool fix = (i0 == 0 && w == 0 && lane == 15);

    float m_run[4] = {-1e30f, -1e30f, -1e30f, -1e30f};
    float l_run[4] = {0.f, 0.f, 0.f, 0.f};
    f32x4 acc[4] = {};
    const f32x4 zero4 = {0.f, 0.f, 0.f, 0.f};

    for (int jt = 0; jt < 16; ++jt) {
        int j0 = jt * 64;
        int w0 = j0 - i0 + 961;            // window base t
        __syncthreads();

        // ---- stage K tile (async HBM->LDS, pre-swizzled source) ----
        {
            const __bf16* ks = kh + (size_t)(bS + j0 + srow) * D_MODEL + n64 + koff;
            GLOAD_LDS(ks,                      (char*)Kt + w*1024);
            GLOAD_LDS(ks + (size_t)32*D_MODEL, (char*)Kt + 4096 + w*1024);
        }
        // ---- stage V^T tile (async HBM->LDS) ----
        {
            const __bf16* vs = vT + (size_t)srow * 1024 + j0 + koff;
            GLOAD_LDS(vs,             (char*)Vt + w*1024);
            GLOAD_LDS(vs + 32*1024,   (char*)Vt + 4096 + w*1024);
        }
        // ---- stage r_head window (register path: needs zero-fill OOB) ----
        if (jt == 0) {
            #pragma unroll
            for (int rep = 0; rep < 4; ++rep) {
                int idx = rep*256 + tid;
                int rowl = idx >> 3;
                int c8  = (idx & 7) * 8;
                int t = w0 + rowl;
                bf8 v = {};
                if (t < T_LEN)
                    v = *(const bf8*)(rhd + (size_t)t * D_MODEL + n64 + c8);
                *(bf8*)((char*)Rw + swz_addr(t & 127, c8*2)) = v;
            }
        } else {
            #pragma unroll
            for (int rep = 0; rep < 2; ++rep) {
                int idx = rep*256 + tid;
                int rowl = idx >> 3;
                int c8  = (idx & 7) * 8;
                int t = w0 + 64 + rowl;
                bf8 v = {};
                if (t < T_LEN)
                    v = *(const bf8*)(rhd + (size_t)t * D_MODEL + n64 + c8);
                *(bf8*)((char*)Rw + swz_addr(t & 127, c8*2)) = v;
            }
        }
        __syncthreads();

        // ---- content scores ----
        f32x4 sc_[4] = {zero4, zero4, zero4, zero4};
        #pragma unroll
        for (int c = 0; c < 4; ++c) {
            #pragma unroll
            for (int kk = 0; kk < 2; ++kk) {
                bf8 kb2 = *(const bf8*)((const char*)Kt + swz_addr(c*16 + lcol, kk*64 + grp*16));
                sc_[c] = __builtin_amdgcn_mfma_f32_16x16x32_bf16(qwA[kk], kb2, sc_[c], 0, 0, 0);
            }
        }
        // ---- positional: 5 window tiles ----
        int a0 = 3 - w;
        f32x4 pacc[5] = {zero4, zero4, zero4, zero4, zero4};
        #pragma unroll
        for (int pa = 0; pa < 5; ++pa) {
            #pragma unroll
            for (int kk = 0; kk < 2; ++kk) {
                int tr = w0 + (a0 + pa) * 16 + lcol;
                bf8 rb2 = *(const bf8*)((const char*)Rw + swz_addr(tr & 127, kk*64 + grp*16));
                pacc[pa] = __builtin_amdgcn_mfma_f32_16x16x32_bf16(qrA[kk], rb2, pacc[pa], 0, 0, 0);
            }
        }
        __bf16* pw = poss + w * 16 * 84;
        #pragma unroll
        for (int pa = 0; pa < 5; ++pa) {
            #pragma unroll
            for (int reg = 0; reg < 4; ++reg)
                pw[(grp*4 + reg) * 84 + pa*16 + lcol] = (__bf16)pacc[pa][reg];
        }
        asm volatile("s_waitcnt lgkmcnt(0)" ::: "memory");
        __builtin_amdgcn_sched_barrier(0);

        // ---- token-type masks (point of use; dead after assemble) ----
        unsigned long long selw[4];
        #pragma unroll
        for (int reg = 0; reg < 4; ++reg) {
            int gi = i0 + w*16 + grp*4 + reg;
            selw[reg] = selpack[(size_t)(bS + gi) * 16 + jt];
        }

        // ---- assemble scores ----
        float sv[4][4];
        if (simple) {
            #pragma unroll
            for (int c = 0; c < 4; ++c) {
                int jl = c*16 + lcol;
                #pragma unroll
                for (int reg = 0; reg < 4; ++reg) {
                    int il = grp*4 + reg;
                    int rr = jl - il + 15;
                    float pv = (float)pw[il * 84 + rr];
                    if (fix && jt == 15 && c == 3 && reg == 0) pv = fixv;
                    float ttv = ((selw[reg] >> jl) & 1ull) ? t1r[reg] : t0r[reg];
                    sv[c][reg] = sc_[c][reg] + pv + ttv;
                }
            }
        } else {
            #pragma unroll
            for (int c = 0; c < 4; ++c) {
                int jl = c*16 + lcol;
                int gj = j0 + jl;
                float ma = maskadd[b * S_LEN + gj];
                #pragma unroll
                for (int reg = 0; reg < 4; ++reg) {
                    int il = grp*4 + reg;
                    int gi = i0 + w*16 + il;
                    int rr = jl - il + 15;
                    float pv = (float)pw[il * 84 + rr];
                    if (fix && jt == 15 && c == 3 && reg == 0) pv = fixv;
                    float clv = (float)clsb[(size_t)gi * S_LEN + gj];
                    float ttv = ((selw[reg] >> jl) & 1ull) ? t1r[reg] : t0r[reg];
                    sv[c][reg] = sc_[c][reg] + clv * (pv + ttv) + ma;
                }
            }
        }

        // ---- online softmax ----
        float mx[4], alpha[4], rs[4];
        #pragma unroll
        for (int reg = 0; reg < 4; ++reg)
            mx[reg] = fmaxf(fmaxf(sv[0][reg], sv[1][reg]), fmaxf(sv[2][reg], sv[3][reg]));
        #pragma unroll
        for (int msk = 1; msk < 16; msk <<= 1) {
            #pragma unroll
            for (int reg = 0; reg < 4; ++reg)
                mx[reg] = fmaxf(mx[reg], __shfl_xor(mx[reg], msk, 64));
        }
        #pragma unroll
        for (int reg = 0; reg < 4; ++reg) {
            float mn = fmaxf(m_run[reg], mx[reg]);
            alpha[reg] = __expf(m_run[reg] - mn);
            m_run[reg] = mn;
            rs[reg] = 0.f;
        }
        __bf16* psw = Ps;
        #pragma unroll
        for (int c = 0; c < 4; ++c) {
            int jl = c*16 + lcol;
            #pragma unroll
            for (int reg = 0; reg < 4; ++reg) {
                int il = grp*4 + reg;
                float p = __expf(sv[c][reg] - m_run[reg]);
                rs[reg] += p;
                *((__bf16*)((char*)psw + w*2048 + swz_addr(il, jl*2))) = (__bf16)p;
            }
        }
        #pragma unroll
        for (int msk = 1; msk < 16; msk <<= 1) {
            #pragma unroll
            for (int reg = 0; reg < 4; ++reg)
                rs[reg] += __shfl_xor(rs[reg], msk, 64);
        }
        #pragma unroll
        for (int reg = 0; reg < 4; ++reg)
            l_run[reg] = l_run[reg] * alpha[reg] + rs[reg];
        #pragma unroll
        for (int c = 0; c < 4; ++c) {
            #pragma unroll
            for (int reg = 0; reg < 4; ++reg) acc[c][reg] *= alpha[reg];
        }
        asm volatile("s_waitcnt lgkmcnt(0)" ::: "memory");
        __builtin_amdgcn_sched_barrier(0);

        // ---- PV ----
        bf8 pA[2];
        #pragma unroll
        for (int kk = 0; kk < 2; ++kk)
            pA[kk] = *(const bf8*)((const char*)psw + w*2048 + swz_addr(lcol, kk*64 + grp*16));
        #pragma unroll
        for (int c = 0; c < 4; ++c) {
            #pragma unroll
            for (int kk = 0; kk < 2; ++kk) {
                bf8 vb2 = *(const bf8*)((const char*)Vt + swz_addr(c*16 + lcol, kk*64 + grp*16));
                acc[c] = __builtin_amdgcn_mfma_f32_16x16x32_bf16(pA[kk], vb2, acc[c], 0, 0, 0);
            }
        }
    }

    // ---- epilogue (bf16 out) ----
    float inv[4];
    #pragma unroll
    for (int reg = 0; reg < 4; ++reg) inv[reg] = 1.f / l_run[reg];
    #pragma unroll
    for (int c = 0; c < 4; ++c) {
        #pragma unroll
        for (int reg = 0; reg < 4; ++reg) {
            size_t o = ((size_t)(bS + i0 + w*16 + grp*4 + reg)) * D_MODEL + n64 + c*16 + lcol;
            av[o] = (__bf16)(acc[c][reg] * inv[reg]);
        }
    }
}

// ---------------------------------------------------------------------------
// LayerNorm(query + attn_out) * g + b
// ---------------------------------------------------------------------------
__global__ __launch_bounds__(256)
void ln_kernel(const float* __restrict__ query, const float* __restrict__ ao,
               const float* __restrict__ gam, const float* __restrict__ bet,
               float* __restrict__ out)
{
    int row = blockIdx.x;
    int tid = threadIdx.x;
    size_t base = (size_t)row * D_MODEL;
    float xv[3];
    float s = 0.f, sq = 0.f;
    #pragma unroll
    for (int k = 0; k < 3; ++k) {
        int c = tid + k * 256;
        float v = query[base + c] + ao[base + c];
        xv[k] = v; s += v; sq += v * v;
    }
    for (int off = 32; off > 0; off >>= 1) {
        s  += __shfl_down(s, off);
        sq += __shfl_down(sq, off);
    }
    __shared__ float rs[4], rq[4];
    __shared__ float mean_s, inv_s;
    int wid = tid >> 6, lane = tid & 63;
    if (lane == 0) { rs[wid] = s; rq[wid] = sq; }
    __syncthreads();
    if (tid == 0) {
        float S0 = rs[0] + rs[1] + rs[2] + rs[3];
        float Q0 = rq[0] + rq[1] + rq[2] + rq[3];
        float mean = S0 / (float)D_MODEL;
        float var  = Q0 / (float)D_MODEL - mean * mean;
        mean_s = mean;
        inv_s  = rsqrtf(var + LN_EPSF);
    }
    __syncthreads();
    float mean = mean_s, inv = inv_s;
    #pragma unroll
    for (int k = 0; k < 3; ++k) {
        int c = tid + k * 256;
        out[base + c] = (xv[k] - mean) * inv * gam[c] + bet[c];
    }
}

// ---------------------------------------------------------------------------
extern "C" void kernel_launch(void* const* d_in, const int* in_sizes, int n_in,
                              void* d_out, int out_size, void* d_ws, size_t ws_size,
                              hipStream_t stream)
{
    const float* query = (const float*)d_in[0];
    const float* key   = (const float*)d_in[1];
    const float* value = (const float*)d_in[2];
    const float* r     = (const float*)d_in[3];
    const void*  ttm   = d_in[4];
    const int*   amask = (const int*)d_in[5];
    const float* cls   = (const float*)d_in[6];
    const float* Wq    = (const float*)d_in[7];
    const float* Wk    = (const float*)d_in[8];
    const float* bk    = (const float*)d_in[9];
    const float* Wv    = (const float*)d_in[10];
    const float* bv    = (const float*)d_in[11];
    const float* Wpost = (const float*)d_in[12];
    const float* bpost = (const float*)d_in[13];
    const float* ln_g  = (const float*)d_in[14];
    const float* ln_b  = (const float*)d_in[15];
    const float* rwb   = (const float*)d_in[16];
    const float* rrb   = (const float*)d_in[17];
    const float* rker  = (const float*)d_in[18];
    const float* rsb   = (const float*)d_in[19];
    const float* seg   = (const float*)d_in[20];

    char* wsb = (char*)d_ws;
    __bf16* qh  = (__bf16*)(wsb);                    //  6,291,456
    __bf16* kh  = (__bf16*)(wsb + 6291456);
    __bf16* vhT = (__bf16*)(wsb + 12582912);         //  6,291,456  [b][n][64 d][1024 j]
    __bf16* rhd = (__bf16*)(wsb + 18874368);         //  3,145,728
    float*  tt  = (float*) (wsb + 22020096);         //    393,216
    __bf16* av  = (__bf16*)(wsb + 22413312);         //  6,291,456 (qin_b before attn)
    float*  ao  = (float*) (wsb + 28704768);         // 12,582,912 (kin_b before post)
    __bf16* Wqt = (__bf16*)(wsb + 41287680);         //  1,179,648 each
    __bf16* Wkt = (__bf16*)(wsb + 42467328);
    __bf16* Wvt = (__bf16*)(wsb + 43646976);
    __bf16* Wpt = (__bf16*)(wsb + 44826624);
    __bf16* rkt = (__bf16*)(wsb + 46006272);
    int*    flag = (int*)  (wsb + 47185920);         //        256
    unsigned long long* selpack = (unsigned long long*)(wsb + 47186176); // 524,288
    __bf16* clsb    = (__bf16*)(wsb + 51380480);                // 2,097,152
    float*  maskadd = (float*) (wsb + 53477632);                //    16,384
    __bf16* rin_b   = (__bf16*)(wsb + 53494016);                // 3,145,728

    // input bf16 copies overlapping later-written buffers (lifetimes disjoint)
    __bf16* qin_b = av;                 // av written by attn (after proj)
    __bf16* kin_b = (__bf16*)ao;        // ao written by post_gemm (after attn)
    __bf16* vin_b = (__bf16*)(wsb + 34996224);

    detect_kernel<<<1, 64, 0, stream>>>((const unsigned char*)ttm, flag);
    tobf16_kernel<<<dim3(1536, 1, 4), 256, 0, stream>>>(query, key, value, r,
                                                        qin_b, kin_b, vin_b, rin_b);
    prep_sel<<<256, 256, 0, stream>>>(ttm, flag, selpack);
    clsb_prep<<<512, 256, 0, stream>>>(cls, amask, clsb, maskadd, flag);

    dim3 gtr(12, 12, 5);
    wtrans_kernel<<<gtr, 256, 0, stream>>>(Wq, Wk, Wv, Wpost, rker,
                                           Wqt, Wkt, Wvt, Wpt, rkt);

    proj_gemm<<<768, 256, 0, stream>>>(qin_b, kin_b, vin_b, rin_b,
                                       Wqt, Wkt, Wvt, rkt, bk, bv,
                                       qh, kh, vhT, rhd);

    ttbias_kernel<<<384, 256, 0, stream>>>(qh, rsb, seg, tt);

    dim3 gattn(16, 12, 4);
    attn_kernel<<<gattn, 256, 0, stream>>>(qh, kh, vhT, rhd, tt, clsb, selpack,
                                           maskadd, rwb, rrb, flag, av);

    post_gemm<<<192, 256, 0, stream>>>(av, Wpt, bpost, ao);

    ln_kernel<<<4096, 256, 0, stream>>>(query, ao, ln_g, ln_b, (float*)d_out);
}

// Round 13
// 170.003 us; speedup vs baseline: 1.4715x; 1.1270x over previous
//
#include <hip/hip_runtime.h>
#include <hip/hip_bf16.h>

#define S_LEN   1024
#define D_MODEL 768
#define N_HEAD  12
#define D_HEAD  64
#define BATCH   4
#define T_LEN   2047      // 2*S-1
#define INF_VAL 1000000.0f
#define SCALE   0.125f    // 1/sqrt(64)
#define LN_EPSF 1e-9f

typedef __attribute__((ext_vector_type(8))) __bf16 bf8;
typedef __attribute__((ext_vector_type(4))) __bf16 bf4;
typedef __attribute__((ext_vector_type(4))) float  f32x4;

// byte-address XOR swizzle for 128B-stride LDS rows
__device__ __forceinline__ int swz_addr(int row, int byte_in_row) {
    return ((row << 7) + byte_in_row) ^ ((row & 7) << 4);
}

#define GLOAD_LDS(gsrc, ldst) \
    __builtin_amdgcn_global_load_lds( \
        (const __attribute__((address_space(1))) void*)(gsrc), \
        (__attribute__((address_space(3))) void*)(ldst), 16, 0, 0)

// ---------------------------------------------------------------------------
// flag[0]: token_type_mat int32(1)/int8(0).  flag[1]: cls==1 && amask==1.
// ---------------------------------------------------------------------------
__global__ void detect_kernel(const unsigned char* __restrict__ p, int* __restrict__ flag)
{
    int lane = threadIdx.x;          // 64 threads
    int nz = 0;
    int base = lane * 64;
    for (int k = base; k < base + 64; k += 4)
        nz += (p[k+1] != 0) + (p[k+2] != 0) + (p[k+3] != 0);
    unsigned long long m = __ballot(nz != 0);
    if (lane == 0) { flag[0] = (m == 0ull) ? 1 : 0; flag[1] = 1; }
}

// ---------------------------------------------------------------------------
// fp32 -> bf16 bulk convert (query,key,value,r) via blockIdx.z
// ---------------------------------------------------------------------------
__global__ __launch_bounds__(256)
void tobf16_kernel(const float* __restrict__ q, const float* __restrict__ k,
                   const float* __restrict__ v, const float* __restrict__ r,
                   __bf16* __restrict__ qb, __bf16* __restrict__ kb,
                   __bf16* __restrict__ vb, __bf16* __restrict__ rb)
{
    int z = blockIdx.z;
    const float* src; __bf16* dst; size_t n;
    if (z == 0)      { src = q; dst = qb; n = (size_t)4096*768; }
    else if (z == 1) { src = k; dst = kb; n = (size_t)4096*768; }
    else if (z == 2) { src = v; dst = vb; n = (size_t)4096*768; }
    else             { src = r; dst = rb; n = (size_t)T_LEN*768; }
    size_t i = ((size_t)blockIdx.x * 256 + threadIdx.x) * 8;
    if (i + 8 > n) return;
    float4 a = *(const float4*)(src + i);
    float4 b = *(const float4*)(src + i + 4);
    bf8 o;
    o[0]=(__bf16)a.x; o[1]=(__bf16)a.y; o[2]=(__bf16)a.z; o[3]=(__bf16)a.w;
    o[4]=(__bf16)b.x; o[5]=(__bf16)b.y; o[6]=(__bf16)b.z; o[7]=(__bf16)b.w;
    *(bf8*)(dst + i) = o;
}

// ---------------------------------------------------------------------------
// selbit[idx] = token_type_mat[idx] ? 1 : 0   (8 elements/thread)
// ---------------------------------------------------------------------------
__global__ __launch_bounds__(256)
void prep_sel(const void* __restrict__ ttm, const int* __restrict__ flag,
              unsigned char* __restrict__ selbit)
{
    size_t idx = ((size_t)blockIdx.x * 256 + threadIdx.x) * 8;
    unsigned long long out = 0;
    if (flag[0]) {
        const int* ip = (const int*)ttm + idx;
        int4 a = *(const int4*)ip;
        int4 b = *(const int4*)(ip + 4);
        out  = (a.x ? 1ull : 0)       | (a.y ? 1ull : 0) << 8
             | (a.z ? 1ull : 0) << 16 | (a.w ? 1ull : 0) << 24
             | (b.x ? 1ull : 0) << 32 | (b.y ? 1ull : 0) << 40
             | (b.z ? 1ull : 0) << 48 | (b.w ? 1ull : 0) << 56;
    } else {
        unsigned long long raw = *(const unsigned long long*)((const unsigned char*)ttm + idx);
        #pragma unroll
        for (int i = 0; i < 8; ++i)
            out |= (((raw >> (8*i)) & 0xffull) ? 1ull : 0) << (8*i);
    }
    *(unsigned long long*)(selbit + idx) = out;
}

// ---------------------------------------------------------------------------
// clsb = bf16(cls); maskadd = -INF*(1-amask); all-ones detection -> flag[1]
// ---------------------------------------------------------------------------
__global__ __launch_bounds__(256)
void clsb_prep(const float* __restrict__ cls, const int* __restrict__ amask,
               __bf16* __restrict__ clsb, float* __restrict__ maskadd,
               int* __restrict__ flag)
{
    size_t idx = ((size_t)blockIdx.x * 256 + threadIdx.x) * 8;
    const float* p = cls + idx;
    float4 a = *(const float4*)p;
    float4 b = *(const float4*)(p + 4);
    bf8 o;
    o[0]=(__bf16)a.x; o[1]=(__bf16)a.y; o[2]=(__bf16)a.z; o[3]=(__bf16)a.w;
    o[4]=(__bf16)b.x; o[5]=(__bf16)b.y; o[6]=(__bf16)b.z; o[7]=(__bf16)b.w;
    *(bf8*)(clsb + idx) = o;
    int ok = (a.x==1.f)&&(a.y==1.f)&&(a.z==1.f)&&(a.w==1.f)
          && (b.x==1.f)&&(b.y==1.f)&&(b.z==1.f)&&(b.w==1.f);
    if (blockIdx.x == 0) {
        for (int j = threadIdx.x; j < BATCH * S_LEN; j += 256) {
            int am = amask[j];
            maskadd[j] = -INF_VAL * (1.f - (float)am);
            ok &= (am == 1);
        }
    }
    ok = __syncthreads_and(ok);
    if (threadIdx.x == 0 && !ok) atomicAnd(flag + 1, 0);
}

// ---------------------------------------------------------------------------
// Wt[n][k] = (bf16) W[k][n]; fused over 5 weight matrices via blockIdx.z
// ---------------------------------------------------------------------------
__global__ __launch_bounds__(256)
void wtrans_kernel(const float* __restrict__ W0, const float* __restrict__ W1,
                   const float* __restrict__ W2, const float* __restrict__ W3,
                   const float* __restrict__ W4,
                   __bf16* __restrict__ T0, __bf16* __restrict__ T1,
                   __bf16* __restrict__ T2, __bf16* __restrict__ T3,
                   __bf16* __restrict__ T4)
{
    const float* W; __bf16* Wt;
    switch (blockIdx.z) {
        case 0: W = W0; Wt = T0; break;
        case 1: W = W1; Wt = T1; break;
        case 2: W = W2; Wt = T2; break;
        case 3: W = W3; Wt = T3; break;
        default: W = W4; Wt = T4; break;
    }
    const int K = 768, N = 768;
    __shared__ float tile[64][65];
    int tid = threadIdx.x;
    int r = tid >> 4, c4 = (tid & 15) * 4;
    int k0 = blockIdx.y * 64, n0 = blockIdx.x * 64;
    #pragma unroll
    for (int rep = 0; rep < 4; ++rep) {
        int row = rep * 16 + r;
        float4 v = *(const float4*)(W + (size_t)(k0 + row) * N + n0 + c4);
        tile[row][c4+0] = v.x; tile[row][c4+1] = v.y;
        tile[row][c4+2] = v.z; tile[row][c4+3] = v.w;
    }
    __syncthreads();
    #pragma unroll
    for (int rep = 0; rep < 4; ++rep) {
        int row = rep * 16 + r;
        bf4 o;
        #pragma unroll
        for (int j = 0; j < 4; ++j) o[j] = (__bf16)tile[c4 + j][row];
        *(bf4*)(Wt + (size_t)(n0 + row) * K + k0 + c4) = o;
    }
}

// ---------------------------------------------------------------------------
// MFMA GEMM tile body (bf16 A), 2-phase register prefetch.
// out_mode: 0 = fp32 row-major, 1 = bf16 row-major,
//           2 = bf16 head-transposed vhT[(b*12+n)*64+d][1024 j]
// ---------------------------------------------------------------------------
__device__ __forceinline__
void gemm_tile_body(const __bf16* __restrict__ A, const __bf16* __restrict__ Bt,
                    const float* __restrict__ bias, void* __restrict__ C,
                    int M, int N, int K, float scale, int has_bias,
                    int out_mode, int m0, int n0, __bf16* As, __bf16* Bs)
{
    int tid = threadIdx.x;
    int lane = tid & 63, w = tid >> 6;
    int grp = lane >> 4, lcol = lane & 15;
    int wm = w >> 1, wn = w & 1;

    auto loadA = [&](int kt, int rep) -> bf8 {
        int id = rep * 256 + tid;
        int row = id >> 3, ch = id & 7;
        int gm = m0 + row; if (gm >= M) gm = M - 1;
        return *(const bf8*)(A + (size_t)gm * K + kt + ch * 8);
    };
    auto loadB = [&](int kt, int rep) -> bf8 {
        int id = rep * 256 + tid;
        int row = id >> 3, ch = id & 7;
        return *(const bf8*)(Bt + (size_t)(n0 + row) * K + kt + ch * 8);
    };

    bf8 aR0 = loadA(0,0), aR1 = loadA(0,1), aR2 = loadA(0,2), aR3 = loadA(0,3);
    bf8 bR0 = loadB(0,0), bR1 = loadB(0,1), bR2 = loadB(0,2), bR3 = loadB(0,3);

    f32x4 acc[4][4] = {};

    for (int kt = 0; kt < K; kt += 64) {
        __syncthreads();
        {   // write phase
            int id0 = tid;
            { int id = 0*256 + id0; int row = id >> 3, ch = id & 7;
              *(bf8*)((char*)As + swz_addr(row, ch*16)) = aR0;
              *(bf8*)((char*)Bs + swz_addr(row, ch*16)) = bR0; }
            { int id = 1*256 + id0; int row = id >> 3, ch = id & 7;
              *(bf8*)((char*)As + swz_addr(row, ch*16)) = aR1;
              *(bf8*)((char*)Bs + swz_addr(row, ch*16)) = bR1; }
            { int id = 2*256 + id0; int row = id >> 3, ch = id & 7;
              *(bf8*)((char*)As + swz_addr(row, ch*16)) = aR2;
              *(bf8*)((char*)Bs + swz_addr(row, ch*16)) = bR2; }
            { int id = 3*256 + id0; int row = id >> 3, ch = id & 7;
              *(bf8*)((char*)As + swz_addr(row, ch*16)) = aR3;
              *(bf8*)((char*)Bs + swz_addr(row, ch*16)) = bR3; }
        }
        __syncthreads();
        if (kt + 64 < K) {
            aR0 = loadA(kt+64,0); aR1 = loadA(kt+64,1); aR2 = loadA(kt+64,2); aR3 = loadA(kt+64,3);
            bR0 = loadB(kt+64,0); bR1 = loadB(kt+64,1); bR2 = loadB(kt+64,2); bR3 = loadB(kt+64,3);
        }
        #pragma unroll
        for (int kk = 0; kk < 2; ++kk) {
            bf8 a[4], bb[4];
            #pragma unroll
            for (int mi = 0; mi < 4; ++mi)
                a[mi] = *(const bf8*)((const char*)As + swz_addr(wm * 64 + mi * 16 + lcol, kk * 64 + grp * 16));
            #pragma unroll
            for (int ni = 0; ni < 4; ++ni)
                bb[ni] = *(const bf8*)((const char*)Bs + swz_addr(wn * 64 + ni * 16 + lcol, kk * 64 + grp * 16));
            #pragma unroll
            for (int mi = 0; mi < 4; ++mi) {
                #pragma unroll
                for (int ni = 0; ni < 4; ++ni)
                    acc[mi][ni] = __builtin_amdgcn_mfma_f32_16x16x32_bf16(a[mi], bb[ni], acc[mi][ni], 0, 0, 0);
            }
        }
    }

    #pragma unroll
    for (int ni = 0; ni < 4; ++ni) {
        int col = n0 + wn * 64 + ni * 16 + lcol;
        float bval = has_bias ? bias[col] : 0.f;
        #pragma unroll
        for (int mi = 0; mi < 4; ++mi) {
            int rbase = m0 + wm * 64 + mi * 16 + grp * 4;
            if (out_mode == 2) {
                int hn = col >> 6, d = col & 63;
                int bb2 = rbase >> 10;
                int j = rbase & 1023;
                bf4 o;
                #pragma unroll
                for (int reg = 0; reg < 4; ++reg)
                    o[reg] = (__bf16)(acc[mi][ni][reg] * scale + bval);
                *(bf4*)((__bf16*)C + ((size_t)(bb2 * N_HEAD + hn) * 64 + d) * 1024 + j) = o;
            } else {
                #pragma unroll
                for (int reg = 0; reg < 4; ++reg) {
                    int row = rbase + reg;
                    if (row < M) {
                        float vv = acc[mi][ni][reg] * scale + bval;
                        if (out_mode == 1) ((__bf16*)C)[(size_t)row * N + col] = (__bf16)vv;
                        else               ((float*)C)[(size_t)row * N + col] = vv;
                    }
                }
            }
        }
    }
}

// ---------------------------------------------------------------------------
// All four projection GEMMs, 1D grid 768, bijective XCD swizzle (768 = 8*96)
// ---------------------------------------------------------------------------
__global__ __launch_bounds__(256, 3)
void proj_gemm(const __bf16* __restrict__ qb, const __bf16* __restrict__ kb,
               const __bf16* __restrict__ vb, const __bf16* __restrict__ rb,
               const __bf16* __restrict__ Wqt, const __bf16* __restrict__ Wkt,
               const __bf16* __restrict__ Wvt, const __bf16* __restrict__ rkt,
               const float* __restrict__ bk, const float* __restrict__ bv,
               __bf16* __restrict__ qh, __bf16* __restrict__ kh,
               __bf16* __restrict__ vhT, __bf16* __restrict__ rhd)
{
    __shared__ __align__(16) __bf16 As[128 * 64];
    __shared__ __align__(16) __bf16 Bs[128 * 64];
    int id = blockIdx.x;
    int wg = (id & 7) * 96 + (id >> 3);    // XCD-contiguous remap
    int z  = wg / 192;
    int rem = wg % 192;
    int by = rem / 6, bx = rem % 6;

    const __bf16* A; const __bf16* Bt; const float* bias; void* C;
    int M; float scale; int has_bias; int omode;
    if (z == 0)      { A = qb; Bt = Wqt; bias = nullptr; C = qh;  M = 4096; scale = SCALE; has_bias = 0; omode = 1; }
    else if (z == 1) { A = kb; Bt = Wkt; bias = bk;      C = kh;  M = 4096; scale = 1.f;   has_bias = 1; omode = 1; }
    else if (z == 2) { A = vb; Bt = Wvt; bias = bv;      C = vhT; M = 4096; scale = 1.f;   has_bias = 1; omode = 2; }
    else             { A = rb; Bt = rkt; bias = nullptr; C = rhd; M = T_LEN; scale = 1.f;  has_bias = 0; omode = 1; }
    int m0 = by * 128, n0 = bx * 128;
    if (m0 >= M) return;
    gemm_tile_body(A, Bt, bias, C, M, 768, 768, scale, has_bias, omode, m0, n0, As, Bs);
}

// ---------------------------------------------------------------------------
// post-projection GEMM, 1D grid 192 (= 8*24), XCD swizzle
// ---------------------------------------------------------------------------
__global__ __launch_bounds__(256, 3)
void post_gemm(const __bf16* __restrict__ av, const __bf16* __restrict__ Wpt,
               const float* __restrict__ bpost, float* __restrict__ ao)
{
    __shared__ __align__(16) __bf16 As[128 * 64];
    __shared__ __align__(16) __bf16 Bs[128 * 64];
    int id = blockIdx.x;
    int wg = (id & 7) * 24 + (id >> 3);
    int by = wg / 6, bx = wg % 6;
    gemm_tile_body(av, Wpt, bpost, ao, 4096, 768, 768, 1.f, 1, 0,
                   by * 128, bx * 128, As, Bs);
}

// ---------------------------------------------------------------------------
// tt[(b*S+i)*NH*2 + n*2 + s2] = sum_h (qh + r_s_bias*scale) * seg_embed
// ---------------------------------------------------------------------------
__global__ __launch_bounds__(256)
void ttbias_kernel(const __bf16* __restrict__ qh, const float* __restrict__ rsb,
                   const float* __restrict__ seg, float* __restrict__ tt)
{
    int idx = blockIdx.x * 256 + threadIdx.x;
    if (idx >= BATCH * S_LEN * N_HEAD * 2) return;
    int s2  = idx & 1;
    int n   = (idx >> 1) % N_HEAD;
    int row = idx / (2 * N_HEAD);
    const __bf16* q  = qh  + (size_t)row * D_MODEL + n * D_HEAD;
    const float* sg = seg + ((size_t)s2 * N_HEAD + n) * D_HEAD;
    const float* rb = rsb + n * D_HEAD;
    float s = 0.f;
    for (int h = 0; h < D_HEAD; ++h) s += ((float)q[h] + rb[h] * SCALE) * sg[h];
    tt[idx] = s;
}

// ---------------------------------------------------------------------------
// MFMA fused attention. grid (16,12,4), 256 thr. R8 structure + async
// global_load_lds staging for K and V (pre-swizzled per-lane source).
// ---------------------------------------------------------------------------
__global__ __launch_bounds__(256, 3)
void attn_kernel(const __bf16* __restrict__ qh, const __bf16* __restrict__ kh,
                 const __bf16* __restrict__ vhT, const __bf16* __restrict__ rhd,
                 const float* __restrict__ tt, const __bf16* __restrict__ clsb,
                 const unsigned char* __restrict__ selbit,
                 const float* __restrict__ maskadd,
                 const float* __restrict__ rwb, const float* __restrict__ rrb,
                 const int* __restrict__ flag, __bf16* __restrict__ av)
{
    __shared__ __align__(16) __bf16 Kt[64*64];       // [j][h]
    __shared__ __align__(16) __bf16 Vt[64*64];       // [d][j]  (transposed)
    __shared__ __align__(16) __bf16 Rw[128*64];      // circular window, phys = t & 127
    __shared__ __align__(16) __bf16 Ps[4*16*64];     // per-wave P [il][jl]
    __shared__ __align__(16) __bf16 poss[4*16*84];   // per-wave pos band, stride 84

    int tid = threadIdx.x;
    int i0 = blockIdx.x * 64;
    int n  = blockIdx.y;
    int b  = blockIdx.z;
    int bS = b * S_LEN;
    int n64 = n * D_HEAD;
    int simple = flag[1];

    int lane = tid & 63, w = tid >> 6;
    int grp = lane >> 4, lcol = lane & 15;

    const __bf16* vT = vhT + (size_t)(b * N_HEAD + n) * 64 * 1024;

    // staging coords: thread covers rows srow, srow+32 with 8-elem chunks.
    // pre-swizzled source offset (elements); (srow+32)&7 == srow&7.
    int srow = tid >> 3;
    int koff = (((tid & 7) * 16) ^ ((srow & 7) << 4)) >> 1;

    // ---- Q fragments ----
    bf8 qwA[2], qrA[2];
    {
        size_t qrow = (size_t)(bS + i0 + w*16 + lcol) * D_MODEL + n64;
        #pragma unroll
        for (int kk = 0; kk < 2; ++kk) {
            int kb = kk*32 + grp*8;
            bf8 qv = *(const bf8*)(qh + qrow + kb);
            const float* wbp = rwb + n64 + kb;
            const float* rbp = rrb + n64 + kb;
            #pragma unroll
            for (int q = 0; q < 8; ++q) {
                float f = (float)qv[q];
                qwA[kk][q] = (__bf16)(f + wbp[q] * SCALE);
                qrA[kk][q] = (__bf16)(f + rbp[q] * SCALE);
            }
        }
    }

    // ---- per-row token-type values (j-independent, hoisted) ----
    float t0r[4], t1r[4];
    #pragma unroll
    for (int reg = 0; reg < 4; ++reg) {
        int gi = i0 + w*16 + grp*4 + reg;
        const float* ttrow = tt + (((size_t)(bS + gi)) * N_HEAD + n) * 2;
        t0r[reg] = ttrow[0];
        t1r[reg] = ttrow[1];
    }

    // ---- relative-shift edge fixup value: qr_row1 . r_head[0] ----
    float fixv = 0.f;
    if (i0 == 0) {
        float qv = (float)qh[((size_t)(bS + 1)) * D_MODEL + n64 + lane] + rrb[n64 + lane] * SCALE;
        float rv = (float)rhd[n64 + lane];
        float t = qv * rv;
        #pragma unroll
        for (int m = 32; m; m >>= 1) t += __shfl_xor(t, m, 64);
        fixv = t;
    }
    bool fix = (i0 == 0 && w == 0 && lane == 15);

    float m_run[4] = {-1e30f, -1e30f, -1e30f, -1e30f};
    float l_run[4] = {0.f, 0.f, 0.f, 0.f};
    f32x4 acc[4] = {};
    const f32x4 zero4 = {0.f, 0.f, 0.f, 0.f};

    for (int jt = 0; jt < 16; ++jt) {
        int j0 = jt * 64;
        int w0 = j0 - i0 + 961;            // window base t
        __syncthreads();

        // ---- stage K tile (async HBM->LDS, pre-swizzled source) ----
        {
            const __bf16* ks = kh + (size_t)(bS + j0 + srow) * D_MODEL + n64 + koff;
            GLOAD_LDS(ks,                      (char*)Kt + w*1024);
            GLOAD_LDS(ks + (size_t)32*D_MODEL, (char*)Kt + 4096 + w*1024);
        }
        // ---- stage V^T tile (async HBM->LDS) ----
        {
            const __bf16* vs = vT + (size_t)srow * 1024 + j0 + koff;
            GLOAD_LDS(vs,             (char*)Vt + w*1024);
            GLOAD_LDS(vs + 32*1024,   (char*)Vt + 4096 + w*1024);
        }
        // ---- stage r_head window (register path: needs zero-fill OOB) ----
        if (jt == 0) {
            #pragma unroll
            for (int rep = 0; rep < 4; ++rep) {
                int idx = rep*256 + tid;
                int rowl = idx >> 3;
                int c8  = (idx & 7) * 8;
                int t = w0 + rowl;
                bf8 v = {};
                if (t < T_LEN)
                    v = *(const bf8*)(rhd + (size_t)t * D_MODEL + n64 + c8);
                *(bf8*)((char*)Rw + swz_addr(t & 127, c8*2)) = v;
            }
        } else {
            #pragma unroll
            for (int rep = 0; rep < 2; ++rep) {
                int idx = rep*256 + tid;
                int rowl = idx >> 3;
                int c8  = (idx & 7) * 8;
                int t = w0 + 64 + rowl;
                bf8 v = {};
                if (t < T_LEN)
                    v = *(const bf8*)(rhd + (size_t)t * D_MODEL + n64 + c8);
                *(bf8*)((char*)Rw + swz_addr(t & 127, c8*2)) = v;
            }
        }
        __syncthreads();

        // ---- content scores ----
        f32x4 sc_[4] = {zero4, zero4, zero4, zero4};
        #pragma unroll
        for (int c = 0; c < 4; ++c) {
            #pragma unroll
            for (int kk = 0; kk < 2; ++kk) {
                bf8 kb2 = *(const bf8*)((const char*)Kt + swz_addr(c*16 + lcol, kk*64 + grp*16));
                sc_[c] = __builtin_amdgcn_mfma_f32_16x16x32_bf16(qwA[kk], kb2, sc_[c], 0, 0, 0);
            }
        }
        // ---- positional: 5 window tiles ----
        int a0 = 3 - w;
        f32x4 pacc[5] = {zero4, zero4, zero4, zero4, zero4};
        #pragma unroll
        for (int pa = 0; pa < 5; ++pa) {
            #pragma unroll
            for (int kk = 0; kk < 2; ++kk) {
                int tr = w0 + (a0 + pa) * 16 + lcol;
                bf8 rb2 = *(const bf8*)((const char*)Rw + swz_addr(tr & 127, kk*64 + grp*16));
                pacc[pa] = __builtin_amdgcn_mfma_f32_16x16x32_bf16(qrA[kk], rb2, pacc[pa], 0, 0, 0);
            }
        }
        __bf16* pw = poss + w * 16 * 84;
        #pragma unroll
        for (int pa = 0; pa < 5; ++pa) {
            #pragma unroll
            for (int reg = 0; reg < 4; ++reg)
                pw[(grp*4 + reg) * 84 + pa*16 + lcol] = (__bf16)pacc[pa][reg];
        }
        asm volatile("s_waitcnt lgkmcnt(0)" ::: "memory");
        __builtin_amdgcn_sched_barrier(0);

        // ---- assemble scores ----
        float sv[4][4];
        if (simple) {
            #pragma unroll
            for (int c = 0; c < 4; ++c) {
                int jl = c*16 + lcol;
                int gj = j0 + jl;
                #pragma unroll
                for (int reg = 0; reg < 4; ++reg) {
                    int il = grp*4 + reg;
                    int gi = i0 + w*16 + il;
                    int rr = jl - il + 15;
                    float pv = (float)pw[il * 84 + rr];
                    if (fix && jt == 15 && c == 3 && reg == 0) pv = fixv;
                    float ttv = selbit[((size_t)(bS + gi)) * S_LEN + gj] ? t1r[reg] : t0r[reg];
                    sv[c][reg] = sc_[c][reg] + pv + ttv;
                }
            }
        } else {
            #pragma unroll
            for (int c = 0; c < 4; ++c) {
                int jl = c*16 + lcol;
                int gj = j0 + jl;
                float ma = maskadd[b * S_LEN + gj];
                #pragma unroll
                for (int reg = 0; reg < 4; ++reg) {
                    int il = grp*4 + reg;
                    int gi = i0 + w*16 + il;
                    int rr = jl - il + 15;
                    float pv = (float)pw[il * 84 + rr];
                    if (fix && jt == 15 && c == 3 && reg == 0) pv = fixv;
                    float clv = (float)clsb[(size_t)gi * S_LEN + gj];
                    float ttv = selbit[((size_t)(bS + gi)) * S_LEN + gj] ? t1r[reg] : t0r[reg];
                    sv[c][reg] = sc_[c][reg] + clv * (pv + ttv) + ma;
                }
            }
        }

        // ---- online softmax ----
        float mx[4], alpha[4], rs[4];
        #pragma unroll
        for (int reg = 0; reg < 4; ++reg)
            mx[reg] = fmaxf(fmaxf(sv[0][reg], sv[1][reg]), fmaxf(sv[2][reg], sv[3][reg]));
        #pragma unroll
        for (int msk = 1; msk < 16; msk <<= 1) {
            #pragma unroll
            for (int reg = 0; reg < 4; ++reg)
                mx[reg] = fmaxf(mx[reg], __shfl_xor(mx[reg], msk, 64));
        }
        #pragma unroll
        for (int reg = 0; reg < 4; ++reg) {
            float mn = fmaxf(m_run[reg], mx[reg]);
            alpha[reg] = __expf(m_run[reg] - mn);
            m_run[reg] = mn;
            rs[reg] = 0.f;
        }
        __bf16* psw = Ps;
        #pragma unroll
        for (int c = 0; c < 4; ++c) {
            int jl = c*16 + lcol;
            #pragma unroll
            for (int reg = 0; reg < 4; ++reg) {
                int il = grp*4 + reg;
                float p = __expf(sv[c][reg] - m_run[reg]);
                rs[reg] += p;
                *((__bf16*)((char*)psw + w*2048 + swz_addr(il, jl*2))) = (__bf16)p;
            }
        }
        #pragma unroll
        for (int msk = 1; msk < 16; msk <<= 1) {
            #pragma unroll
            for (int reg = 0; reg < 4; ++reg)
                rs[reg] += __shfl_xor(rs[reg], msk, 64);
        }
        #pragma unroll
        for (int reg = 0; reg < 4; ++reg)
            l_run[reg] = l_run[reg] * alpha[reg] + rs[reg];
        #pragma unroll
        for (int c = 0; c < 4; ++c) {
            #pragma unroll
            for (int reg = 0; reg < 4; ++reg) acc[c][reg] *= alpha[reg];
        }
        asm volatile("s_waitcnt lgkmcnt(0)" ::: "memory");
        __builtin_amdgcn_sched_barrier(0);

        // ---- PV ----
        bf8 pA[2];
        #pragma unroll
        for (int kk = 0; kk < 2; ++kk)
            pA[kk] = *(const bf8*)((const char*)psw + w*2048 + swz_addr(lcol, kk*64 + grp*16));
        #pragma unroll
        for (int c = 0; c < 4; ++c) {
            #pragma unroll
            for (int kk = 0; kk < 2; ++kk) {
                bf8 vb2 = *(const bf8*)((const char*)Vt + swz_addr(c*16 + lcol, kk*64 + grp*16));
                acc[c] = __builtin_amdgcn_mfma_f32_16x16x32_bf16(pA[kk], vb2, acc[c], 0, 0, 0);
            }
        }
    }

    // ---- epilogue (bf16 out) ----
    float inv[4];
    #pragma unroll
    for (int reg = 0; reg < 4; ++reg) inv[reg] = 1.f / l_run[reg];
    #pragma unroll
    for (int c = 0; c < 4; ++c) {
        #pragma unroll
        for (int reg = 0; reg < 4; ++reg) {
            size_t o = ((size_t)(bS + i0 + w*16 + grp*4 + reg)) * D_MODEL + n64 + c*16 + lcol;
            av[o] = (__bf16)(acc[c][reg] * inv[reg]);
        }
    }
}

// ---------------------------------------------------------------------------
// LayerNorm(query + attn_out) * g + b
// ---------------------------------------------------------------------------
__global__ __launch_bounds__(256)
void ln_kernel(const float* __restrict__ query, const float* __restrict__ ao,
               const float* __restrict__ gam, const float* __restrict__ bet,
               float* __restrict__ out)
{
    int row = blockIdx.x;
    int tid = threadIdx.x;
    size_t base = (size_t)row * D_MODEL;
    float xv[3];
    float s = 0.f, sq = 0.f;
    #pragma unroll
    for (int k = 0; k < 3; ++k) {
        int c = tid + k * 256;
        float v = query[base + c] + ao[base + c];
        xv[k] = v; s += v; sq += v * v;
    }
    for (int off = 32; off > 0; off >>= 1) {
        s  += __shfl_down(s, off);
        sq += __shfl_down(sq, off);
    }
    __shared__ float rs[4], rq[4];
    __shared__ float mean_s, inv_s;
    int wid = tid >> 6, lane = tid & 63;
    if (lane == 0) { rs[wid] = s; rq[wid] = sq; }
    __syncthreads();
    if (tid == 0) {
        float S0 = rs[0] + rs[1] + rs[2] + rs[3];
        float Q0 = rq[0] + rq[1] + rq[2] + rq[3];
        float mean = S0 / (float)D_MODEL;
        float var  = Q0 / (float)D_MODEL - mean * mean;
        mean_s = mean;
        inv_s  = rsqrtf(var + LN_EPSF);
    }
    __syncthreads();
    float mean = mean_s, inv = inv_s;
    #pragma unroll
    for (int k = 0; k < 3; ++k) {
        int c = tid + k * 256;
        out[base + c] = (xv[k] - mean) * inv * gam[c] + bet[c];
    }
}

// ---------------------------------------------------------------------------
extern "C" void kernel_launch(void* const* d_in, const int* in_sizes, int n_in,
                              void* d_out, int out_size, void* d_ws, size_t ws_size,
                              hipStream_t stream)
{
    const float* query = (const float*)d_in[0];
    const float* key   = (const float*)d_in[1];
    const float* value = (const float*)d_in[2];
    const float* r     = (const float*)d_in[3];
    const void*  ttm   = d_in[4];
    const int*   amask = (const int*)d_in[5];
    const float* cls   = (const float*)d_in[6];
    const float* Wq    = (const float*)d_in[7];
    const float* Wk    = (const float*)d_in[8];
    const float* bk    = (const float*)d_in[9];
    const float* Wv    = (const float*)d_in[10];
    const float* bv    = (const float*)d_in[11];
    const float* Wpost = (const float*)d_in[12];
    const float* bpost = (const float*)d_in[13];
    const float* ln_g  = (const float*)d_in[14];
    const float* ln_b  = (const float*)d_in[15];
    const float* rwb   = (const float*)d_in[16];
    const float* rrb   = (const float*)d_in[17];
    const float* rker  = (const float*)d_in[18];
    const float* rsb   = (const float*)d_in[19];
    const float* seg   = (const float*)d_in[20];

    char* wsb = (char*)d_ws;
    __bf16* qh  = (__bf16*)(wsb);                    //  6,291,456
    __bf16* kh  = (__bf16*)(wsb + 6291456);
    __bf16* vhT = (__bf16*)(wsb + 12582912);         //  6,291,456  [b][n][64 d][1024 j]
    __bf16* rhd = (__bf16*)(wsb + 18874368);         //  3,145,728
    float*  tt  = (float*) (wsb + 22020096);         //    393,216
    __bf16* av  = (__bf16*)(wsb + 22413312);         //  6,291,456 (qin_b before attn)
    float*  ao  = (float*) (wsb + 28704768);         // 12,582,912 (kin_b before post)
    __bf16* Wqt = (__bf16*)(wsb + 41287680);         //  1,179,648 each
    __bf16* Wkt = (__bf16*)(wsb + 42467328);
    __bf16* Wvt = (__bf16*)(wsb + 43646976);
    __bf16* Wpt = (__bf16*)(wsb + 44826624);
    __bf16* rkt = (__bf16*)(wsb + 46006272);
    int*    flag = (int*)  (wsb + 47185920);         //        256
    unsigned char* selbit = (unsigned char*)(wsb + 47186176);   // 4,194,304
    __bf16* clsb    = (__bf16*)(wsb + 51380480);                // 2,097,152
    float*  maskadd = (float*) (wsb + 53477632);                //    16,384
    __bf16* rin_b   = (__bf16*)(wsb + 53494016);                // 3,145,728

    // input bf16 copies overlapping later-written buffers (lifetimes disjoint)
    __bf16* qin_b = av;                 // av written by attn (after proj)
    __bf16* kin_b = (__bf16*)ao;        // ao written by post_gemm (after attn)
    __bf16* vin_b = (__bf16*)(wsb + 34996224);

    detect_kernel<<<1, 64, 0, stream>>>((const unsigned char*)ttm, flag);
    tobf16_kernel<<<dim3(1536, 1, 4), 256, 0, stream>>>(query, key, value, r,
                                                        qin_b, kin_b, vin_b, rin_b);
    prep_sel<<<2048, 256, 0, stream>>>(ttm, flag, selbit);
    clsb_prep<<<512, 256, 0, stream>>>(cls, amask, clsb, maskadd, flag);

    dim3 gtr(12, 12, 5);
    wtrans_kernel<<<gtr, 256, 0, stream>>>(Wq, Wk, Wv, Wpost, rker,
                                           Wqt, Wkt, Wvt, Wpt, rkt);

    proj_gemm<<<768, 256, 0, stream>>>(qin_b, kin_b, vin_b, rin_b,
                                       Wqt, Wkt, Wvt, rkt, bk, bv,
                                       qh, kh, vhT, rhd);

    ttbias_kernel<<<384, 256, 0, stream>>>(qh, rsb, seg, tt);

    dim3 gattn(16, 12, 4);
    attn_kernel<<<gattn, 256, 0, stream>>>(qh, kh, vhT, rhd, tt, clsb, selbit,
                                           maskadd, rwb, rrb, flag, av);

    post_gemm<<<192, 256, 0, stream>>>(av, Wpt, bpost, ao);

    ln_kernel<<<4096, 256, 0, stream>>>(query, ao, ln_g, ln_b, (float*)d_out);
}

// Round 14
// 164.048 us; speedup vs baseline: 1.5249x; 1.0363x over previous
//
#include <hip/hip_runtime.h>
#include <hip/hip_bf16.h>

#define S_LEN   1024
#define D_MODEL 768
#define N_HEAD  12
#define D_HEAD  64
#define BATCH   4
#define T_LEN   2047      // 2*S-1
#define INF_VAL 1000000.0f
#define SCALE   0.125f    // 1/sqrt(64)
#define LN_EPSF 1e-9f

typedef __attribute__((ext_vector_type(8))) __bf16 bf8;
typedef __attribute__((ext_vector_type(4))) __bf16 bf4;
typedef __attribute__((ext_vector_type(4))) float  f32x4;

// byte-address XOR swizzle for 128B-stride LDS rows
__device__ __forceinline__ int swz_addr(int row, int byte_in_row) {
    return ((row << 7) + byte_in_row) ^ ((row & 7) << 4);
}

#define GLOAD_LDS(gsrc, ldst) \
    __builtin_amdgcn_global_load_lds( \
        (const __attribute__((address_space(1))) void*)(gsrc), \
        (__attribute__((address_space(3))) void*)(ldst), 16, 0, 0)

// ---------------------------------------------------------------------------
// flag[0]: token_type_mat int32(1)/int8(0).  flag[1]: cls==1 && amask==1.
// ---------------------------------------------------------------------------
__global__ void detect_kernel(const unsigned char* __restrict__ p, int* __restrict__ flag)
{
    int lane = threadIdx.x;          // 64 threads
    int nz = 0;
    int base = lane * 64;
    for (int k = base; k < base + 64; k += 4)
        nz += (p[k+1] != 0) + (p[k+2] != 0) + (p[k+3] != 0);
    unsigned long long m = __ballot(nz != 0);
    if (lane == 0) { flag[0] = (m == 0ull) ? 1 : 0; flag[1] = 1; }
}

// ---------------------------------------------------------------------------
// Fused preprocessing: one dispatch, blockIdx.x-range partitioned.
//  [0,6144)     : fp32->bf16 convert of query/key/value/r
//  [6144,8192)  : selbit (token-type 0/1 bytes)
//  [8192,8704)  : clsb bf16 + maskadd + all-ones detect
//  [8704,9424)  : 5x weight transpose W[k][n] -> Wt[n][k] bf16
// ---------------------------------------------------------------------------
__global__ __launch_bounds__(256)
void prep_fused(const float* __restrict__ q, const float* __restrict__ k,
                const float* __restrict__ v, const float* __restrict__ r,
                __bf16* __restrict__ qb, __bf16* __restrict__ kb,
                __bf16* __restrict__ vb, __bf16* __restrict__ rb,
                const void* __restrict__ ttm, unsigned char* __restrict__ selbit,
                const float* __restrict__ cls, const int* __restrict__ amask,
                __bf16* __restrict__ clsb, float* __restrict__ maskadd,
                int* __restrict__ flag,
                const float* __restrict__ W0, const float* __restrict__ W1,
                const float* __restrict__ W2, const float* __restrict__ W3,
                const float* __restrict__ W4,
                __bf16* __restrict__ T0, __bf16* __restrict__ T1,
                __bf16* __restrict__ T2, __bf16* __restrict__ T3,
                __bf16* __restrict__ T4)
{
    __shared__ float tile[64][65];
    int fb = blockIdx.x;

    if (fb < 6144) {
        // ---- tobf16 ----
        int z  = fb / 1536;
        int bx = fb % 1536;
        const float* src; __bf16* dst; size_t n;
        if (z == 0)      { src = q; dst = qb; n = (size_t)4096*768; }
        else if (z == 1) { src = k; dst = kb; n = (size_t)4096*768; }
        else if (z == 2) { src = v; dst = vb; n = (size_t)4096*768; }
        else             { src = r; dst = rb; n = (size_t)T_LEN*768; }
        size_t i = ((size_t)bx * 256 + threadIdx.x) * 8;
        if (i + 8 > n) return;
        float4 a = *(const float4*)(src + i);
        float4 b = *(const float4*)(src + i + 4);
        bf8 o;
        o[0]=(__bf16)a.x; o[1]=(__bf16)a.y; o[2]=(__bf16)a.z; o[3]=(__bf16)a.w;
        o[4]=(__bf16)b.x; o[5]=(__bf16)b.y; o[6]=(__bf16)b.z; o[7]=(__bf16)b.w;
        *(bf8*)(dst + i) = o;
    } else if (fb < 8192) {
        // ---- prep_sel ----
        int bx = fb - 6144;
        size_t idx = ((size_t)bx * 256 + threadIdx.x) * 8;
        unsigned long long out = 0;
        if (flag[0]) {
            const int* ip = (const int*)ttm + idx;
            int4 a = *(const int4*)ip;
            int4 b = *(const int4*)(ip + 4);
            out  = (a.x ? 1ull : 0)       | (a.y ? 1ull : 0) << 8
                 | (a.z ? 1ull : 0) << 16 | (a.w ? 1ull : 0) << 24
                 | (b.x ? 1ull : 0) << 32 | (b.y ? 1ull : 0) << 40
                 | (b.z ? 1ull : 0) << 48 | (b.w ? 1ull : 0) << 56;
        } else {
            unsigned long long raw = *(const unsigned long long*)((const unsigned char*)ttm + idx);
            #pragma unroll
            for (int i = 0; i < 8; ++i)
                out |= (((raw >> (8*i)) & 0xffull) ? 1ull : 0) << (8*i);
        }
        *(unsigned long long*)(selbit + idx) = out;
    } else if (fb < 8704) {
        // ---- clsb_prep ----
        int bx = fb - 8192;
        size_t idx = ((size_t)bx * 256 + threadIdx.x) * 8;
        const float* p = cls + idx;
        float4 a = *(const float4*)p;
        float4 b = *(const float4*)(p + 4);
        bf8 o;
        o[0]=(__bf16)a.x; o[1]=(__bf16)a.y; o[2]=(__bf16)a.z; o[3]=(__bf16)a.w;
        o[4]=(__bf16)b.x; o[5]=(__bf16)b.y; o[6]=(__bf16)b.z; o[7]=(__bf16)b.w;
        *(bf8*)(clsb + idx) = o;
        int ok = (a.x==1.f)&&(a.y==1.f)&&(a.z==1.f)&&(a.w==1.f)
              && (b.x==1.f)&&(b.y==1.f)&&(b.z==1.f)&&(b.w==1.f);
        if (bx == 0) {
            for (int j = threadIdx.x; j < BATCH * S_LEN; j += 256) {
                int am = amask[j];
                maskadd[j] = -INF_VAL * (1.f - (float)am);
                ok &= (am == 1);
            }
        }
        ok = __syncthreads_and(ok);
        if (threadIdx.x == 0 && !ok) atomicAnd(flag + 1, 0);
    } else {
        // ---- wtrans (5 matrices) ----
        int id = fb - 8704;             // [0,720)
        int zz = id / 144;
        int rem = id % 144;
        int byy = rem / 12, bxx = rem % 12;
        const float* W; __bf16* Wt;
        switch (zz) {
            case 0: W = W0; Wt = T0; break;
            case 1: W = W1; Wt = T1; break;
            case 2: W = W2; Wt = T2; break;
            case 3: W = W3; Wt = T3; break;
            default: W = W4; Wt = T4; break;
        }
        const int K = 768, N = 768;
        int tid = threadIdx.x;
        int rr = tid >> 4, c4 = (tid & 15) * 4;
        int k0 = byy * 64, n0 = bxx * 64;
        #pragma unroll
        for (int rep = 0; rep < 4; ++rep) {
            int row = rep * 16 + rr;
            float4 vv = *(const float4*)(W + (size_t)(k0 + row) * N + n0 + c4);
            tile[row][c4+0] = vv.x; tile[row][c4+1] = vv.y;
            tile[row][c4+2] = vv.z; tile[row][c4+3] = vv.w;
        }
        __syncthreads();
        #pragma unroll
        for (int rep = 0; rep < 4; ++rep) {
            int row = rep * 16 + rr;
            bf4 o;
            #pragma unroll
            for (int j = 0; j < 4; ++j) o[j] = (__bf16)tile[c4 + j][row];
            *(bf4*)(Wt + (size_t)(n0 + row) * K + k0 + c4) = o;
        }
    }
}

// ---------------------------------------------------------------------------
// MFMA GEMM tile body (bf16 A), 2-phase register prefetch.
// out_mode: 0 = fp32 row-major, 1 = bf16 row-major,
//           2 = bf16 head-transposed vhT[(b*12+n)*64+d][1024 j]
// ---------------------------------------------------------------------------
__device__ __forceinline__
void gemm_tile_body(const __bf16* __restrict__ A, const __bf16* __restrict__ Bt,
                    const float* __restrict__ bias, void* __restrict__ C,
                    int M, int N, int K, float scale, int has_bias,
                    int out_mode, int m0, int n0, __bf16* As, __bf16* Bs)
{
    int tid = threadIdx.x;
    int lane = tid & 63, w = tid >> 6;
    int grp = lane >> 4, lcol = lane & 15;
    int wm = w >> 1, wn = w & 1;

    auto loadA = [&](int kt, int rep) -> bf8 {
        int id = rep * 256 + tid;
        int row = id >> 3, ch = id & 7;
        int gm = m0 + row; if (gm >= M) gm = M - 1;
        return *(const bf8*)(A + (size_t)gm * K + kt + ch * 8);
    };
    auto loadB = [&](int kt, int rep) -> bf8 {
        int id = rep * 256 + tid;
        int row = id >> 3, ch = id & 7;
        return *(const bf8*)(Bt + (size_t)(n0 + row) * K + kt + ch * 8);
    };

    bf8 aR0 = loadA(0,0), aR1 = loadA(0,1), aR2 = loadA(0,2), aR3 = loadA(0,3);
    bf8 bR0 = loadB(0,0), bR1 = loadB(0,1), bR2 = loadB(0,2), bR3 = loadB(0,3);

    f32x4 acc[4][4] = {};

    for (int kt = 0; kt < K; kt += 64) {
        __syncthreads();
        {   // write phase
            int id0 = tid;
            { int id = 0*256 + id0; int row = id >> 3, ch = id & 7;
              *(bf8*)((char*)As + swz_addr(row, ch*16)) = aR0;
              *(bf8*)((char*)Bs + swz_addr(row, ch*16)) = bR0; }
            { int id = 1*256 + id0; int row = id >> 3, ch = id & 7;
              *(bf8*)((char*)As + swz_addr(row, ch*16)) = aR1;
              *(bf8*)((char*)Bs + swz_addr(row, ch*16)) = bR1; }
            { int id = 2*256 + id0; int row = id >> 3, ch = id & 7;
              *(bf8*)((char*)As + swz_addr(row, ch*16)) = aR2;
              *(bf8*)((char*)Bs + swz_addr(row, ch*16)) = bR2; }
            { int id = 3*256 + id0; int row = id >> 3, ch = id & 7;
              *(bf8*)((char*)As + swz_addr(row, ch*16)) = aR3;
              *(bf8*)((char*)Bs + swz_addr(row, ch*16)) = bR3; }
        }
        __syncthreads();
        if (kt + 64 < K) {
            aR0 = loadA(kt+64,0); aR1 = loadA(kt+64,1); aR2 = loadA(kt+64,2); aR3 = loadA(kt+64,3);
            bR0 = loadB(kt+64,0); bR1 = loadB(kt+64,1); bR2 = loadB(kt+64,2); bR3 = loadB(kt+64,3);
        }
        #pragma unroll
        for (int kk = 0; kk < 2; ++kk) {
            bf8 a[4], bb[4];
            #pragma unroll
            for (int mi = 0; mi < 4; ++mi)
                a[mi] = *(const bf8*)((const char*)As + swz_addr(wm * 64 + mi * 16 + lcol, kk * 64 + grp * 16));
            #pragma unroll
            for (int ni = 0; ni < 4; ++ni)
                bb[ni] = *(const bf8*)((const char*)Bs + swz_addr(wn * 64 + ni * 16 + lcol, kk * 64 + grp * 16));
            #pragma unroll
            for (int mi = 0; mi < 4; ++mi) {
                #pragma unroll
                for (int ni = 0; ni < 4; ++ni)
                    acc[mi][ni] = __builtin_amdgcn_mfma_f32_16x16x32_bf16(a[mi], bb[ni], acc[mi][ni], 0, 0, 0);
            }
        }
    }

    #pragma unroll
    for (int ni = 0; ni < 4; ++ni) {
        int col = n0 + wn * 64 + ni * 16 + lcol;
        float bval = has_bias ? bias[col] : 0.f;
        #pragma unroll
        for (int mi = 0; mi < 4; ++mi) {
            int rbase = m0 + wm * 64 + mi * 16 + grp * 4;
            if (out_mode == 2) {
                int hn = col >> 6, d = col & 63;
                int bb2 = rbase >> 10;
                int j = rbase & 1023;
                bf4 o;
                #pragma unroll
                for (int reg = 0; reg < 4; ++reg)
                    o[reg] = (__bf16)(acc[mi][ni][reg] * scale + bval);
                *(bf4*)((__bf16*)C + ((size_t)(bb2 * N_HEAD + hn) * 64 + d) * 1024 + j) = o;
            } else {
                #pragma unroll
                for (int reg = 0; reg < 4; ++reg) {
                    int row = rbase + reg;
                    if (row < M) {
                        float vv = acc[mi][ni][reg] * scale + bval;
                        if (out_mode == 1) ((__bf16*)C)[(size_t)row * N + col] = (__bf16)vv;
                        else               ((float*)C)[(size_t)row * N + col] = vv;
                    }
                }
            }
        }
    }
}

// ---------------------------------------------------------------------------
// All four projection GEMMs, 1D grid 768, bijective XCD swizzle (768 = 8*96)
// ---------------------------------------------------------------------------
__global__ __launch_bounds__(256, 3)
void proj_gemm(const __bf16* __restrict__ qb, const __bf16* __restrict__ kb,
               const __bf16* __restrict__ vb, const __bf16* __restrict__ rb,
               const __bf16* __restrict__ Wqt, const __bf16* __restrict__ Wkt,
               const __bf16* __restrict__ Wvt, const __bf16* __restrict__ rkt,
               const float* __restrict__ bk, const float* __restrict__ bv,
               __bf16* __restrict__ qh, __bf16* __restrict__ kh,
               __bf16* __restrict__ vhT, __bf16* __restrict__ rhd)
{
    __shared__ __align__(16) __bf16 As[128 * 64];
    __shared__ __align__(16) __bf16 Bs[128 * 64];
    int id = blockIdx.x;
    int wg = (id & 7) * 96 + (id >> 3);    // XCD-contiguous remap
    int z  = wg / 192;
    int rem = wg % 192;
    int by = rem / 6, bx = rem % 6;

    const __bf16* A; const __bf16* Bt; const float* bias; void* C;
    int M; float scale; int has_bias; int omode;
    if (z == 0)      { A = qb; Bt = Wqt; bias = nullptr; C = qh;  M = 4096; scale = SCALE; has_bias = 0; omode = 1; }
    else if (z == 1) { A = kb; Bt = Wkt; bias = bk;      C = kh;  M = 4096; scale = 1.f;   has_bias = 1; omode = 1; }
    else if (z == 2) { A = vb; Bt = Wvt; bias = bv;      C = vhT; M = 4096; scale = 1.f;   has_bias = 1; omode = 2; }
    else             { A = rb; Bt = rkt; bias = nullptr; C = rhd; M = T_LEN; scale = 1.f;  has_bias = 0; omode = 1; }
    int m0 = by * 128, n0 = bx * 128;
    if (m0 >= M) return;
    gemm_tile_body(A, Bt, bias, C, M, 768, 768, scale, has_bias, omode, m0, n0, As, Bs);
}

// ---------------------------------------------------------------------------
// post-projection GEMM, 1D grid 192 (= 8*24), XCD swizzle
// ---------------------------------------------------------------------------
__global__ __launch_bounds__(256, 3)
void post_gemm(const __bf16* __restrict__ av, const __bf16* __restrict__ Wpt,
               const float* __restrict__ bpost, float* __restrict__ ao)
{
    __shared__ __align__(16) __bf16 As[128 * 64];
    __shared__ __align__(16) __bf16 Bs[128 * 64];
    int id = blockIdx.x;
    int wg = (id & 7) * 24 + (id >> 3);
    int by = wg / 6, bx = wg % 6;
    gemm_tile_body(av, Wpt, bpost, ao, 4096, 768, 768, 1.f, 1, 0,
                   by * 128, bx * 128, As, Bs);
}

// ---------------------------------------------------------------------------
// tt[(b*S+i)*NH*2 + n*2 + s2] = sum_h (qh + r_s_bias*scale) * seg_embed
// ---------------------------------------------------------------------------
__global__ __launch_bounds__(256)
void ttbias_kernel(const __bf16* __restrict__ qh, const float* __restrict__ rsb,
                   const float* __restrict__ seg, float* __restrict__ tt)
{
    int idx = blockIdx.x * 256 + threadIdx.x;
    if (idx >= BATCH * S_LEN * N_HEAD * 2) return;
    int s2  = idx & 1;
    int n   = (idx >> 1) % N_HEAD;
    int row = idx / (2 * N_HEAD);
    const __bf16* q  = qh  + (size_t)row * D_MODEL + n * D_HEAD;
    const float* sg = seg + ((size_t)s2 * N_HEAD + n) * D_HEAD;
    const float* rb = rsb + n * D_HEAD;
    float s = 0.f;
    for (int h = 0; h < D_HEAD; ++h) s += ((float)q[h] + rb[h] * SCALE) * sg[h];
    tt[idx] = s;
}

// ---------------------------------------------------------------------------
// MFMA fused attention. grid (16,12,4), 256 thr. R8 structure + async
// global_load_lds staging for K and V (pre-swizzled per-lane source).
// ---------------------------------------------------------------------------
__global__ __launch_bounds__(256, 3)
void attn_kernel(const __bf16* __restrict__ qh, const __bf16* __restrict__ kh,
                 const __bf16* __restrict__ vhT, const __bf16* __restrict__ rhd,
                 const float* __restrict__ tt, const __bf16* __restrict__ clsb,
                 const unsigned char* __restrict__ selbit,
                 const float* __restrict__ maskadd,
                 const float* __restrict__ rwb, const float* __restrict__ rrb,
                 const int* __restrict__ flag, __bf16* __restrict__ av)
{
    __shared__ __align__(16) __bf16 Kt[64*64];       // [j][h]
    __shared__ __align__(16) __bf16 Vt[64*64];       // [d][j]  (transposed)
    __shared__ __align__(16) __bf16 Rw[128*64];      // circular window, phys = t & 127
    __shared__ __align__(16) __bf16 Ps[4*16*64];     // per-wave P [il][jl]
    __shared__ __align__(16) __bf16 poss[4*16*84];   // per-wave pos band, stride 84

    int tid = threadIdx.x;
    int i0 = blockIdx.x * 64;
    int n  = blockIdx.y;
    int b  = blockIdx.z;
    int bS = b * S_LEN;
    int n64 = n * D_HEAD;
    int simple = flag[1];

    int lane = tid & 63, w = tid >> 6;
    int grp = lane >> 4, lcol = lane & 15;

    const __bf16* vT = vhT + (size_t)(b * N_HEAD + n) * 64 * 1024;

    // staging coords: thread covers rows srow, srow+32 with 8-elem chunks.
    // pre-swizzled source offset (elements); (srow+32)&7 == srow&7.
    int srow = tid >> 3;
    int koff = (((tid & 7) * 16) ^ ((srow & 7) << 4)) >> 1;

    // ---- Q fragments ----
    bf8 qwA[2], qrA[2];
    {
        size_t qrow = (size_t)(bS + i0 + w*16 + lcol) * D_MODEL + n64;
        #pragma unroll
        for (int kk = 0; kk < 2; ++kk) {
            int kb = kk*32 + grp*8;
            bf8 qv = *(const bf8*)(qh + qrow + kb);
            const float* wbp = rwb + n64 + kb;
            const float* rbp = rrb + n64 + kb;
            #pragma unroll
            for (int q = 0; q < 8; ++q) {
                float f = (float)qv[q];
                qwA[kk][q] = (__bf16)(f + wbp[q] * SCALE);
                qrA[kk][q] = (__bf16)(f + rbp[q] * SCALE);
            }
        }
    }

    // ---- per-row token-type values (j-independent, hoisted) ----
    float t0r[4], t1r[4];
    #pragma unroll
    for (int reg = 0; reg < 4; ++reg) {
        int gi = i0 + w*16 + grp*4 + reg;
        const float* ttrow = tt + (((size_t)(bS + gi)) * N_HEAD + n) * 2;
        t0r[reg] = ttrow[0];
        t1r[reg] = ttrow[1];
    }

    // ---- relative-shift edge fixup value: qr_row1 . r_head[0] ----
    float fixv = 0.f;
    if (i0 == 0) {
        float qv = (float)qh[((size_t)(bS + 1)) * D_MODEL + n64 + lane] + rrb[n64 + lane] * SCALE;
        float rv = (float)rhd[n64 + lane];
        float t = qv * rv;
        #pragma unroll
        for (int m = 32; m; m >>= 1) t += __shfl_xor(t, m, 64);
        fixv = t;
    }
    bool fix = (i0 == 0 && w == 0 && lane == 15);

    float m_run[4] = {-1e30f, -1e30f, -1e30f, -1e30f};
    float l_run[4] = {0.f, 0.f, 0.f, 0.f};
    f32x4 acc[4] = {};
    const f32x4 zero4 = {0.f, 0.f, 0.f, 0.f};

    for (int jt = 0; jt < 16; ++jt) {
        int j0 = jt * 64;
        int w0 = j0 - i0 + 961;            // window base t
        __syncthreads();

        // ---- stage K tile (async HBM->LDS, pre-swizzled source) ----
        {
            const __bf16* ks = kh + (size_t)(bS + j0 + srow) * D_MODEL + n64 + koff;
            GLOAD_LDS(ks,                      (char*)Kt + w*1024);
            GLOAD_LDS(ks + (size_t)32*D_MODEL, (char*)Kt + 4096 + w*1024);
        }
        // ---- stage V^T tile (async HBM->LDS) ----
        {
            const __bf16* vs = vT + (size_t)srow * 1024 + j0 + koff;
            GLOAD_LDS(vs,             (char*)Vt + w*1024);
            GLOAD_LDS(vs + 32*1024,   (char*)Vt + 4096 + w*1024);
        }
        // ---- stage r_head window (register path: needs zero-fill OOB) ----
        if (jt == 0) {
            #pragma unroll
            for (int rep = 0; rep < 4; ++rep) {
                int idx = rep*256 + tid;
                int rowl = idx >> 3;
                int c8  = (idx & 7) * 8;
                int t = w0 + rowl;
                bf8 v = {};
                if (t < T_LEN)
                    v = *(const bf8*)(rhd + (size_t)t * D_MODEL + n64 + c8);
                *(bf8*)((char*)Rw + swz_addr(t & 127, c8*2)) = v;
            }
        } else {
            #pragma unroll
            for (int rep = 0; rep < 2; ++rep) {
                int idx = rep*256 + tid;
                int rowl = idx >> 3;
                int c8  = (idx & 7) * 8;
                int t = w0 + 64 + rowl;
                bf8 v = {};
                if (t < T_LEN)
                    v = *(const bf8*)(rhd + (size_t)t * D_MODEL + n64 + c8);
                *(bf8*)((char*)Rw + swz_addr(t & 127, c8*2)) = v;
            }
        }
        __syncthreads();

        // ---- content scores ----
        f32x4 sc_[4] = {zero4, zero4, zero4, zero4};
        #pragma unroll
        for (int c = 0; c < 4; ++c) {
            #pragma unroll
            for (int kk = 0; kk < 2; ++kk) {
                bf8 kb2 = *(const bf8*)((const char*)Kt + swz_addr(c*16 + lcol, kk*64 + grp*16));
                sc_[c] = __builtin_amdgcn_mfma_f32_16x16x32_bf16(qwA[kk], kb2, sc_[c], 0, 0, 0);
            }
        }
        // ---- positional: 5 window tiles ----
        int a0 = 3 - w;
        f32x4 pacc[5] = {zero4, zero4, zero4, zero4, zero4};
        #pragma unroll
        for (int pa = 0; pa < 5; ++pa) {
            #pragma unroll
            for (int kk = 0; kk < 2; ++kk) {
                int tr = w0 + (a0 + pa) * 16 + lcol;
                bf8 rb2 = *(const bf8*)((const char*)Rw + swz_addr(tr & 127, kk*64 + grp*16));
                pacc[pa] = __builtin_amdgcn_mfma_f32_16x16x32_bf16(qrA[kk], rb2, pacc[pa], 0, 0, 0);
            }
        }
        __bf16* pw = poss + w * 16 * 84;
        #pragma unroll
        for (int pa = 0; pa < 5; ++pa) {
            #pragma unroll
            for (int reg = 0; reg < 4; ++reg)
                pw[(grp*4 + reg) * 84 + pa*16 + lcol] = (__bf16)pacc[pa][reg];
        }
        asm volatile("s_waitcnt lgkmcnt(0)" ::: "memory");
        __builtin_amdgcn_sched_barrier(0);

        // ---- assemble scores ----
        float sv[4][4];
        if (simple) {
            #pragma unroll
            for (int c = 0; c < 4; ++c) {
                int jl = c*16 + lcol;
                int gj = j0 + jl;
                #pragma unroll
                for (int reg = 0; reg < 4; ++reg) {
                    int il = grp*4 + reg;
                    int gi = i0 + w*16 + il;
                    int rr = jl - il + 15;
                    float pv = (float)pw[il * 84 + rr];
                    if (fix && jt == 15 && c == 3 && reg == 0) pv = fixv;
                    float ttv = selbit[((size_t)(bS + gi)) * S_LEN + gj] ? t1r[reg] : t0r[reg];
                    sv[c][reg] = sc_[c][reg] + pv + ttv;
                }
            }
        } else {
            #pragma unroll
            for (int c = 0; c < 4; ++c) {
                int jl = c*16 + lcol;
                int gj = j0 + jl;
                float ma = maskadd[b * S_LEN + gj];
                #pragma unroll
                for (int reg = 0; reg < 4; ++reg) {
                    int il = grp*4 + reg;
                    int gi = i0 + w*16 + il;
                    int rr = jl - il + 15;
                    float pv = (float)pw[il * 84 + rr];
                    if (fix && jt == 15 && c == 3 && reg == 0) pv = fixv;
                    float clv = (float)clsb[(size_t)gi * S_LEN + gj];
                    float ttv = selbit[((size_t)(bS + gi)) * S_LEN + gj] ? t1r[reg] : t0r[reg];
                    sv[c][reg] = sc_[c][reg] + clv * (pv + ttv) + ma;
                }
            }
        }

        // ---- online softmax ----
        float mx[4], alpha[4], rs[4];
        #pragma unroll
        for (int reg = 0; reg < 4; ++reg)
            mx[reg] = fmaxf(fmaxf(sv[0][reg], sv[1][reg]), fmaxf(sv[2][reg], sv[3][reg]));
        #pragma unroll
        for (int msk = 1; msk < 16; msk <<= 1) {
            #pragma unroll
            for (int reg = 0; reg < 4; ++reg)
                mx[reg] = fmaxf(mx[reg], __shfl_xor(mx[reg], msk, 64));
        }
        #pragma unroll
        for (int reg = 0; reg < 4; ++reg) {
            float mn = fmaxf(m_run[reg], mx[reg]);
            alpha[reg] = __expf(m_run[reg] - mn);
            m_run[reg] = mn;
            rs[reg] = 0.f;
        }
        __bf16* psw = Ps;
        #pragma unroll
        for (int c = 0; c < 4; ++c) {
            int jl = c*16 + lcol;
            #pragma unroll
            for (int reg = 0; reg < 4; ++reg) {
                int il = grp*4 + reg;
                float p = __expf(sv[c][reg] - m_run[reg]);
                rs[reg] += p;
                *((__bf16*)((char*)psw + w*2048 + swz_addr(il, jl*2))) = (__bf16)p;
            }
        }
        #pragma unroll
        for (int msk = 1; msk < 16; msk <<= 1) {
            #pragma unroll
            for (int reg = 0; reg < 4; ++reg)
                rs[reg] += __shfl_xor(rs[reg], msk, 64);
        }
        #pragma unroll
        for (int reg = 0; reg < 4; ++reg)
            l_run[reg] = l_run[reg] * alpha[reg] + rs[reg];
        #pragma unroll
        for (int c = 0; c < 4; ++c) {
            #pragma unroll
            for (int reg = 0; reg < 4; ++reg) acc[c][reg] *= alpha[reg];
        }
        asm volatile("s_waitcnt lgkmcnt(0)" ::: "memory");
        __builtin_amdgcn_sched_barrier(0);

        // ---- PV ----
        bf8 pA[2];
        #pragma unroll
        for (int kk = 0; kk < 2; ++kk)
            pA[kk] = *(const bf8*)((const char*)psw + w*2048 + swz_addr(lcol, kk*64 + grp*16));
        #pragma unroll
        for (int c = 0; c < 4; ++c) {
            #pragma unroll
            for (int kk = 0; kk < 2; ++kk) {
                bf8 vb2 = *(const bf8*)((const char*)Vt + swz_addr(c*16 + lcol, kk*64 + grp*16));
                acc[c] = __builtin_amdgcn_mfma_f32_16x16x32_bf16(pA[kk], vb2, acc[c], 0, 0, 0);
            }
        }
    }

    // ---- epilogue (bf16 out) ----
    float inv[4];
    #pragma unroll
    for (int reg = 0; reg < 4; ++reg) inv[reg] = 1.f / l_run[reg];
    #pragma unroll
    for (int c = 0; c < 4; ++c) {
        #pragma unroll
        for (int reg = 0; reg < 4; ++reg) {
            size_t o = ((size_t)(bS + i0 + w*16 + grp*4 + reg)) * D_MODEL + n64 + c*16 + lcol;
            av[o] = (__bf16)(acc[c][reg] * inv[reg]);
        }
    }
}

// ---------------------------------------------------------------------------
// LayerNorm(query + attn_out) * g + b
// ---------------------------------------------------------------------------
__global__ __launch_bounds__(256)
void ln_kernel(const float* __restrict__ query, const float* __restrict__ ao,
               const float* __restrict__ gam, const float* __restrict__ bet,
               float* __restrict__ out)
{
    int row = blockIdx.x;
    int tid = threadIdx.x;
    size_t base = (size_t)row * D_MODEL;
    float xv[3];
    float s = 0.f, sq = 0.f;
    #pragma unroll
    for (int k = 0; k < 3; ++k) {
        int c = tid + k * 256;
        float v = query[base + c] + ao[base + c];
        xv[k] = v; s += v; sq += v * v;
    }
    for (int off = 32; off > 0; off >>= 1) {
        s  += __shfl_down(s, off);
        sq += __shfl_down(sq, off);
    }
    __shared__ float rs[4], rq[4];
    __shared__ float mean_s, inv_s;
    int wid = tid >> 6, lane = tid & 63;
    if (lane == 0) { rs[wid] = s; rq[wid] = sq; }
    __syncthreads();
    if (tid == 0) {
        float S0 = rs[0] + rs[1] + rs[2] + rs[3];
        float Q0 = rq[0] + rq[1] + rq[2] + rq[3];
        float mean = S0 / (float)D_MODEL;
        float var  = Q0 / (float)D_MODEL - mean * mean;
        mean_s = mean;
        inv_s  = rsqrtf(var + LN_EPSF);
    }
    __syncthreads();
    float mean = mean_s, inv = inv_s;
    #pragma unroll
    for (int k = 0; k < 3; ++k) {
        int c = tid + k * 256;
        out[base + c] = (xv[k] - mean) * inv * gam[c] + bet[c];
    }
}

// ---------------------------------------------------------------------------
extern "C" void kernel_launch(void* const* d_in, const int* in_sizes, int n_in,
                              void* d_out, int out_size, void* d_ws, size_t ws_size,
                              hipStream_t stream)
{
    const float* query = (const float*)d_in[0];
    const float* key   = (const float*)d_in[1];
    const float* value = (const float*)d_in[2];
    const float* r     = (const float*)d_in[3];
    const void*  ttm   = d_in[4];
    const int*   amask = (const int*)d_in[5];
    const float* cls   = (const float*)d_in[6];
    const float* Wq    = (const float*)d_in[7];
    const float* Wk    = (const float*)d_in[8];
    const float* bk    = (const float*)d_in[9];
    const float* Wv    = (const float*)d_in[10];
    const float* bv    = (const float*)d_in[11];
    const float* Wpost = (const float*)d_in[12];
    const float* bpost = (const float*)d_in[13];
    const float* ln_g  = (const float*)d_in[14];
    const float* ln_b  = (const float*)d_in[15];
    const float* rwb   = (const float*)d_in[16];
    const float* rrb   = (const float*)d_in[17];
    const float* rker  = (const float*)d_in[18];
    const float* rsb   = (const float*)d_in[19];
    const float* seg   = (const float*)d_in[20];

    char* wsb = (char*)d_ws;
    __bf16* qh  = (__bf16*)(wsb);                    //  6,291,456
    __bf16* kh  = (__bf16*)(wsb + 6291456);
    __bf16* vhT = (__bf16*)(wsb + 12582912);         //  6,291,456  [b][n][64 d][1024 j]
    __bf16* rhd = (__bf16*)(wsb + 18874368);         //  3,145,728
    float*  tt  = (float*) (wsb + 22020096);         //    393,216
    __bf16* av  = (__bf16*)(wsb + 22413312);         //  6,291,456 (qin_b before attn)
    float*  ao  = (float*) (wsb + 28704768);         // 12,582,912 (kin_b before post)
    __bf16* Wqt = (__bf16*)(wsb + 41287680);         //  1,179,648 each
    __bf16* Wkt = (__bf16*)(wsb + 42467328);
    __bf16* Wvt = (__bf16*)(wsb + 43646976);
    __bf16* Wpt = (__bf16*)(wsb + 44826624);
    __bf16* rkt = (__bf16*)(wsb + 46006272);
    int*    flag = (int*)  (wsb + 47185920);         //        256
    unsigned char* selbit = (unsigned char*)(wsb + 47186176);   // 4,194,304
    __bf16* clsb    = (__bf16*)(wsb + 51380480);                // 2,097,152
    float*  maskadd = (float*) (wsb + 53477632);                //    16,384
    __bf16* rin_b   = (__bf16*)(wsb + 53494016);                // 3,145,728

    // input bf16 copies overlapping later-written buffers (lifetimes disjoint)
    __bf16* qin_b = av;                 // av written by attn (after proj)
    __bf16* kin_b = (__bf16*)ao;        // ao written by post_gemm (after attn)
    __bf16* vin_b = (__bf16*)(wsb + 34996224);

    detect_kernel<<<1, 64, 0, stream>>>((const unsigned char*)ttm, flag);

    prep_fused<<<9424, 256, 0, stream>>>(query, key, value, r,
                                         qin_b, kin_b, vin_b, rin_b,
                                         ttm, selbit,
                                         cls, amask, clsb, maskadd, flag,
                                         Wq, Wk, Wv, Wpost, rker,
                                         Wqt, Wkt, Wvt, Wpt, rkt);

    proj_gemm<<<768, 256, 0, stream>>>(qin_b, kin_b, vin_b, rin_b,
                                       Wqt, Wkt, Wvt, rkt, bk, bv,
                                       qh, kh, vhT, rhd);

    ttbias_kernel<<<384, 256, 0, stream>>>(qh, rsb, seg, tt);

    dim3 gattn(16, 12, 4);
    attn_kernel<<<gattn, 256, 0, stream>>>(qh, kh, vhT, rhd, tt, clsb, selbit,
                                           maskadd, rwb, rrb, flag, av);

    post_gemm<<<192, 256, 0, stream>>>(av, Wpt, bpost, ao);

    ln_kernel<<<4096, 256, 0, stream>>>(query, ao, ln_g, ln_b, (float*)d_out);
}